// Round 11
// baseline (566.431 us; speedup 1.0000x reference)
//
#include <hip/hip_runtime.h>
#include <cstdint>

typedef __bf16 bf16_t;
typedef bf16_t bf16x8 __attribute__((ext_vector_type(8)));
typedef float floatx4 __attribute__((ext_vector_type(4)));
typedef unsigned short ushort4v __attribute__((ext_vector_type(4)));

constexpr int N_NODES = 50000;
constexpr int N_EDGES = 800000;
constexpr int HID = 128;
constexpr int EH = 64;
constexpr int NCH = (N_NODES + 255) / 256;  // 196 scan chunks

__device__ __forceinline__ float silu_f(float x) {
    return x * __builtin_amdgcn_rcpf(1.0f + __expf(-x));
}

// ---------------------------------------------------------------------------
// Fused weight pack: all 6 weight tensors -> bf16 MFMA B-fragment order.
// ---------------------------------------------------------------------------
__global__ __launch_bounds__(256) void pack_all_kernel(
    const float* __restrict__ embin, const float* __restrict__ embout,
    const float* __restrict__ ew1, const float* __restrict__ ew2,
    const float* __restrict__ nw1, const float* __restrict__ nw2,
    bf16_t* __restrict__ pk)
{
    int t = blockIdx.x * 256 + threadIdx.x;
    const float* W; int K, Nc; int base; bf16_t* out;
    if (t < 1024)       { W = embin;  K = 64;  Nc = 128; base = 0;     out = pk; }
    else if (t < 2048)  { W = embout; K = 128; Nc = 64;  base = 1024;  out = pk + 8192; }
    else if (t < 10240) { W = ew1;    K = 256; Nc = 64;  base = 2048;  out = pk + 16384; }
    else if (t < 12288) { W = ew2;    K = 64;  Nc = 64;  base = 10240; out = pk + 81920; }
    else if (t < 24576) { W = nw1;    K = 192; Nc = 128; base = 12288; out = pk + 98304; }
    else                { W = nw2;    K = 128; Nc = 128; base = 24576; out = pk + 196608; }
    t -= base;
    int KS = K >> 5, NT = Nc >> 4;
    int lane = t & 63;
    int chunk = t >> 6;
    int ks = chunk % KS;
    int nt = (chunk / KS) % NT;
    int l  = chunk / (KS * NT);
    int quad = lane >> 4, coln = lane & 15;
    const float* Wl = W + l * K * Nc;
    bf16x8 v;
#pragma unroll
    for (int j = 0; j < 8; j++)
        v[j] = (bf16_t)Wl[(ks * 32 + quad * 8 + j) * Nc + nt * 16 + coln];
    *(bf16x8*)(out + t * 8) = v;
}

// ---------------------------------------------------------------------------
// Counting sort of edges by destination (row), masked dests only.
// ---------------------------------------------------------------------------
__global__ void hist2_kernel(const int* __restrict__ ea, const int* __restrict__ eb,
                             const int* __restrict__ ma, const int* __restrict__ mb,
                             int* __restrict__ ba, int* __restrict__ bb) {
    int half = gridDim.x >> 1;
    int b = blockIdx.x;
    const int* erows; const int* mask; int* bins;
    if (b < half) { erows = ea; mask = ma; bins = ba; }
    else          { erows = eb; mask = mb; bins = bb; b -= half; }
    int i = b * 256 + threadIdx.x;
    if (i >= N_EDGES) return;
    int r = erows[i];
    if (mask[r] != 0) atomicAdd(&bins[r], 1);
}

__global__ __launch_bounds__(256) void scan_phase1(
    const int* __restrict__ bins_a, const int* __restrict__ bins_b,
    int* __restrict__ bs_a, int* __restrict__ bs_b) {
    const int* bins = blockIdx.y ? bins_b : bins_a;
    int* bs = blockIdx.y ? bs_b : bs_a;
    int i = blockIdx.x * 256 + threadIdx.x;
    int v = (i < N_NODES) ? bins[i] : 0;
#pragma unroll
    for (int off = 32; off; off >>= 1) v += __shfl_down(v, off, 64);
    __shared__ int ws_[4];
    int lane = threadIdx.x & 63, wv = threadIdx.x >> 6;
    if (lane == 0) ws_[wv] = v;
    __syncthreads();
    if (threadIdx.x == 0) bs[blockIdx.x] = ws_[0] + ws_[1] + ws_[2] + ws_[3];
}

__global__ __launch_bounds__(256) void scan_phase2(
    int* __restrict__ bs_a, int* __restrict__ bs_b,
    int* __restrict__ bins_a, int* __restrict__ bins_b) {
    int* bs = blockIdx.x ? bs_b : bs_a;
    int* bins = blockIdx.x ? bins_b : bins_a;
    int t = threadIdx.x, lane = t & 63, wv = t >> 6;
    int v = (t < NCH) ? bs[t] : 0;
    int s = v;
#pragma unroll
    for (int off = 1; off < 64; off <<= 1) {
        int u = __shfl_up(s, off, 64);
        if (lane >= off) s += u;
    }
    __shared__ int wsum[4];
    if (lane == 63) wsum[wv] = s;
    __syncthreads();
    int woff = 0;
    for (int w = 0; w < wv; w++) woff += wsum[w];
    int excl = s - v + woff;
    if (t < NCH) bs[t] = excl;
    if (t == NCH - 1) bins[N_NODES] = excl + v;  // total kept-edge count M
}

__global__ __launch_bounds__(256) void scan_phase3(
    int* __restrict__ bins_a, int* __restrict__ bins_b,
    const int* __restrict__ bs_a, const int* __restrict__ bs_b) {
    int* bins = blockIdx.y ? bins_b : bins_a;
    const int* bs = blockIdx.y ? bs_b : bs_a;
    int i = blockIdx.x * 256 + threadIdx.x;
    int t = threadIdx.x, lane = t & 63, wv = t >> 6;
    int v = (i < N_NODES) ? bins[i] : 0;
    int s = v;
#pragma unroll
    for (int off = 1; off < 64; off <<= 1) {
        int u = __shfl_up(s, off, 64);
        if (lane >= off) s += u;
    }
    __shared__ int wsum[4];
    if (lane == 63) wsum[wv] = s;
    __syncthreads();
    int woff = 0;
    for (int w = 0; w < wv; w++) woff += wsum[w];
    if (i < N_NODES) bins[i] = s - v + woff + bs[blockIdx.x];
}

// src reconstruction: node r owns positions [bins[r], bins[r+1]) — dense fill.
// MUST run before scatter2 (which mutates bins).
__global__ void fill_src_kernel(const int* __restrict__ bins_a, const int* __restrict__ bins_b,
                                int* __restrict__ ssrc_a, int* __restrict__ ssrc_b) {
    const int* bins = blockIdx.y ? bins_b : bins_a;
    int* ssrc = blockIdx.y ? ssrc_b : ssrc_a;
    int r = blockIdx.x * 256 + threadIdx.x;
    if (r >= N_NODES) return;
    int p0 = bins[r], p1 = bins[r + 1];
    for (int p = p0; p < p1; p++) ssrc[p] = r;
}

// scatter: only the dst column (4B) goes through the random-position store
__global__ void scatter2_kernel(const int* __restrict__ ea, const int* __restrict__ eb,
                                const int* __restrict__ ma, const int* __restrict__ mb,
                                int* __restrict__ ba, int* __restrict__ bb,
                                int* __restrict__ sdst_a, int* __restrict__ sdst_b) {
    int half = gridDim.x >> 1;
    int b = blockIdx.x;
    const int* e; const int* mask; int* bins; int* sdst;
    if (b < half) { e = ea; mask = ma; bins = ba; sdst = sdst_a; }
    else          { e = eb; mask = mb; bins = bb; sdst = sdst_b; b -= half; }
    int i = b * 256 + threadIdx.x;
    if (i >= N_EDGES) return;
    int r = e[i];
    if (mask[r] == 0) return;
    int c = e[N_EDGES + i];
    int pos = atomicAdd(&bins[r], 1);
    sdst[pos] = c;
}

// ---------------------------------------------------------------------------
// emb_in: h0[N,64] @ W[64,128] + b -> h (fp32) and h_bf (bf16)
// ---------------------------------------------------------------------------
__global__ __launch_bounds__(256) void emb_in_kernel(
    const float* __restrict__ h0, const bf16_t* __restrict__ wp,
    const float* __restrict__ bias, float* __restrict__ h, bf16_t* __restrict__ h_bf)
{
    int t = threadIdx.x, wave = t >> 6, lane = t & 63;
    int quad = lane >> 4, col = lane & 15;
    int m0 = blockIdx.x * 64 + wave * 16;
    int ndc = min(m0 + col, N_NODES - 1);
    floatx4 acc[8] = {};
#pragma unroll
    for (int ks = 0; ks < 2; ks++) {
        const float* ap = h0 + ndc * 64 + ks * 32 + quad * 8;
        floatx4 f0 = *(const floatx4*)ap;
        floatx4 f1 = *(const floatx4*)(ap + 4);
        bf16x8 a;
#pragma unroll
        for (int j = 0; j < 4; j++) { a[j] = (bf16_t)f0[j]; a[j + 4] = (bf16_t)f1[j]; }
#pragma unroll
        for (int nt = 0; nt < 8; nt++) {
            bf16x8 b = ((const bf16x8*)wp)[(nt * 2 + ks) * 64 + lane];
            acc[nt] = __builtin_amdgcn_mfma_f32_16x16x32_bf16(a, b, acc[nt], 0, 0, 0);
        }
    }
#pragma unroll
    for (int r = 0; r < 4; r++) {
        int nd2 = m0 + quad * 4 + r;
        if (nd2 < N_NODES) {
#pragma unroll
            for (int nt = 0; nt < 8; nt++) {
                int n = nt * 16 + col;
                float x = acc[nt][r] + bias[n];
                h[nd2 * HID + n] = x;
                h_bf[nd2 * HID + n] = (bf16_t)x;
            }
        }
    }
}

// ---------------------------------------------------------------------------
// Sorted edge kernel v7: v6 + dynamic work-stealing (8 padded counters per
// launch, wave-granular claims) to remove the 4.07-tiles/wave tail quantization.
// ---------------------------------------------------------------------------
__global__ __launch_bounds__(256, 3) void edge_kernel_sorted(
    const bf16_t* __restrict__ h_bf, const int* __restrict__ ssrc,
    const int* __restrict__ sdst, const int* __restrict__ m_ptr,
    const bf16_t* __restrict__ w1p, const float* __restrict__ b1,
    const bf16_t* __restrict__ w2p, const float* __restrict__ b2,
    float* __restrict__ agg, float C, int* __restrict__ ctr)
{
    __shared__ __align__(16) bf16_t w1s[16384];        // 32 KB GEMM1 B-frags
    __shared__ __align__(16) bf16_t pool[4][64 * 40];  // per-wave hl/mbT union

    int t = threadIdx.x;
#pragma unroll
    for (int i = 0; i < 8; i++)
        ((bf16x8*)w1s)[t + 256 * i] = ((const bf16x8*)w1p)[t + 256 * i];
    __syncthreads();  // once

    int wave = t >> 6, lane = t & 63, quad = lane >> 4, col = lane & 15;
    bf16_t* hl = pool[wave];   // GEMM1->GEMM2 transpose, stride 72
    bf16_t* mbT = pool[wave];  // messages transposed [n][e], stride 40

    float b1v[4], b2v[4];
#pragma unroll
    for (int nt = 0; nt < 4; nt++) { b1v[nt] = b1[nt * 16 + col]; b2v[nt] = b2[nt * 16 + col]; }

    int M = m_ptr[0];
    int ntiles = (M + 31) >> 5;
    int part = blockIdx.x & 7;
    int* myctr = ctr + part * 16;  // 64B-spread counters

    // claim: tile = part + c*8
    int c0;
    if (lane == 0) c0 = atomicAdd(myctr, 1);
    c0 = __shfl(c0, 0, 64);
    int cur = part + c0 * 8;
    if (cur >= ntiles) return;

    // prologue: load tile cur's edges + gather its A-frags
    int sr = 0x7fffffff, ds = 0x7fffffff;
    { int p = cur * 32 + lane; if (lane < 32 && p < M) { sr = ssrc[p]; ds = sdst[p]; } }
    bf16x8 a[2][8];
    {
        int ns0 = min(__shfl(sr, col, 64), N_NODES - 1);
        int ns1 = min(__shfl(sr, 16 + col, 64), N_NODES - 1);
        int nd0 = min(__shfl(ds, col, 64), N_NODES - 1);
        int nd1 = min(__shfl(ds, 16 + col, 64), N_NODES - 1);
#pragma unroll
        for (int ks = 0; ks < 8; ks++) {
            int o = (ks & 3) * 32 + quad * 8;
            a[0][ks] = *(const bf16x8*)(h_bf + (ks < 4 ? ns0 : nd0) * HID + o);
            a[1][ks] = *(const bf16x8*)(h_bf + (ks < 4 ? ns1 : nd1) * HID + o);
        }
    }

    while (true) {
        // claim next tile; prefetch its edges (latency overlapped with GEMM1)
        int cn;
        if (lane == 0) cn = atomicAdd(myctr, 1);
        cn = __shfl(cn, 0, 64);
        int nxt = part + cn * 8;
        bool have = nxt < ntiles;
        int tl = have ? nxt : cur;  // dummy-but-valid addr when done
        int srn = 0x7fffffff, dsn = 0x7fffffff;
        { int p = tl * 32 + lane; if (lane < 32 && p < M) { srn = ssrc[p]; dsn = sdst[p]; } }

        // GEMM1
        floatx4 acc[2][4] = {};
#pragma unroll
        for (int ks = 0; ks < 8; ks++) {
#pragma unroll
            for (int nt = 0; nt < 4; nt++) {
                bf16x8 b = ((const bf16x8*)w1s)[(nt * 8 + ks) * 64 + lane];
                acc[0][nt] = __builtin_amdgcn_mfma_f32_16x16x32_bf16(a[0][ks], b, acc[0][nt], 0, 0, 0);
                acc[1][nt] = __builtin_amdgcn_mfma_f32_16x16x32_bf16(a[1][ks], b, acc[1][nt], 0, 0, 0);
            }
        }

        // next tile's gathers — in flight under epilogues/GEMM2
        bf16x8 an[2][8];
        {
            int ns0 = min(__shfl(srn, col, 64), N_NODES - 1);
            int ns1 = min(__shfl(srn, 16 + col, 64), N_NODES - 1);
            int nd0 = min(__shfl(dsn, col, 64), N_NODES - 1);
            int nd1 = min(__shfl(dsn, 16 + col, 64), N_NODES - 1);
#pragma unroll
            for (int ks = 0; ks < 8; ks++) {
                int o = (ks & 3) * 32 + quad * 8;
                an[0][ks] = *(const bf16x8*)(h_bf + (ks < 4 ? ns0 : nd0) * HID + o);
                an[1][ks] = *(const bf16x8*)(h_bf + (ks < 4 ? ns1 : nd1) * HID + o);
            }
        }

        // epilogue1: C-layout -> A-layout (wave-local LDS, stride 72)
#pragma unroll
        for (int m = 0; m < 2; m++)
#pragma unroll
            for (int nt = 0; nt < 4; nt++)
#pragma unroll
                for (int r = 0; r < 4; r++)
                    hl[(m * 16 + quad * 4 + r) * 72 + nt * 16 + col] =
                        (bf16_t)silu_f(acc[m][nt][r] + b1v[nt]);

        floatx4 acc2[2][4] = {};
#pragma unroll
        for (int ks = 0; ks < 2; ks++) {
            bf16x8 a2[2];
#pragma unroll
            for (int m = 0; m < 2; m++)
                a2[m] = *(const bf16x8*)(hl + (m * 16 + col) * 72 + ks * 32 + quad * 8);
#pragma unroll
            for (int nt = 0; nt < 4; nt++) {
                bf16x8 b = ((const bf16x8*)w2p)[(nt * 2 + ks) * 64 + lane];
                acc2[0][nt] = __builtin_amdgcn_mfma_f32_16x16x32_bf16(a2[0], b, acc2[0][nt], 0, 0, 0);
                acc2[1][nt] = __builtin_amdgcn_mfma_f32_16x16x32_bf16(a2[1], b, acc2[1][nt], 0, 0, 0);
            }
        }
        // epilogue2: messages TRANSPOSED mbT[n][e], 4 r-values per b64 write
#pragma unroll
        for (int m = 0; m < 2; m++)
#pragma unroll
            for (int nt = 0; nt < 4; nt++) {
                ushort4v p;
#pragma unroll
                for (int r = 0; r < 4; r++) {
                    bf16_t bv = (bf16_t)(silu_f(acc2[m][nt][r] + b2v[nt]) * C);
                    p[r] = __builtin_bit_cast(unsigned short, bv);
                }
                *(ushort4v*)(mbT + (nt * 16 + col) * 40 + m * 16 + quad * 4) = p;
            }

        // combine: preload full column, then pure-VALU run-length scan
        {
            float mv[32];
#pragma unroll
            for (int i = 0; i < 4; i++) {
                bf16x8 v8 = *(const bf16x8*)(mbT + lane * 40 + i * 8);
#pragma unroll
                for (int j = 0; j < 8; j++) mv[i * 8 + j] = (float)v8[j];
            }
            int dp = __shfl(sr, 0, 64);
            float run = mv[0];
#pragma unroll
            for (int r = 1; r < 32; r++) {
                int d = __shfl(sr, r, 64);
                if (d != dp) {  // wave-uniform: coalesced atomic bursts
                    if (dp < N_NODES) atomicAdd(agg + dp * EH + lane, run);
                    run = mv[r]; dp = d;
                } else run += mv[r];
            }
            if (dp < N_NODES) atomicAdd(agg + dp * EH + lane, run);
        }

        if (!have) break;
        cur = nxt; sr = srn; ds = dsn;
#pragma unroll
        for (int m = 0; m < 2; m++)
#pragma unroll
            for (int ks = 0; ks < 8; ks++) a[m][ks] = an[m][ks];
    }
}

// ---------------------------------------------------------------------------
// Fallback (unsorted) edge kernel — used only if ws_size is too small.
// ---------------------------------------------------------------------------
__global__ __launch_bounds__(256) void edge_kernel(
    const bf16_t* __restrict__ h_bf, const int* __restrict__ edges,
    const int* __restrict__ mask,
    const bf16_t* __restrict__ w1p, const float* __restrict__ b1,
    const bf16_t* __restrict__ w2p, const float* __restrict__ b2,
    float* __restrict__ agg, float C)
{
    __shared__ __align__(16) bf16_t w1s[16384];
    __shared__ __align__(16) bf16_t w2s[4096];
    __shared__ __align__(16) bf16_t hl[4][16 * 72];

    int t = threadIdx.x;
#pragma unroll
    for (int i = 0; i < 8; i++)
        ((bf16x8*)w1s)[t + 256 * i] = ((const bf16x8*)w1p)[t + 256 * i];
#pragma unroll
    for (int i = 0; i < 2; i++)
        ((bf16x8*)w2s)[t + 256 * i] = ((const bf16x8*)w2p)[t + 256 * i];
    __syncthreads();

    int wave = t >> 6, lane = t & 63, quad = lane >> 4, col = lane & 15;
    bf16_t* myhl = hl[wave];

    float b1v[4], b2v[4];
#pragma unroll
    for (int nt = 0; nt < 4; nt++) { b1v[nt] = b1[nt * 16 + col]; b2v[nt] = b2[nt * 16 + col]; }

    const int ntile_cnt = N_EDGES / 64;
    for (int tile = blockIdx.x; tile < ntile_cnt; tile += gridDim.x) {
        int ebase = tile * 64 + wave * 16;
        int src = edges[ebase + col];
        int dst = edges[N_EDGES + ebase + col];

        floatx4 acc[4] = {};
#pragma unroll
        for (int ks = 0; ks < 8; ks++) {
            int idx = (ks < 4) ? src : dst;
            bf16x8 a = *(const bf16x8*)(h_bf + idx * HID + (ks & 3) * 32 + quad * 8);
#pragma unroll
            for (int nt = 0; nt < 4; nt++) {
                bf16x8 b = ((const bf16x8*)w1s)[(nt * 8 + ks) * 64 + lane];
                acc[nt] = __builtin_amdgcn_mfma_f32_16x16x32_bf16(a, b, acc[nt], 0, 0, 0);
            }
        }
#pragma unroll
        for (int nt = 0; nt < 4; nt++)
#pragma unroll
            for (int r = 0; r < 4; r++)
                myhl[(quad * 4 + r) * 72 + nt * 16 + col] = (bf16_t)silu_f(acc[nt][r] + b1v[nt]);
        __syncthreads();

        floatx4 acc2[4] = {};
#pragma unroll
        for (int ks = 0; ks < 2; ks++) {
            bf16x8 a = *(const bf16x8*)(myhl + col * 72 + ks * 32 + quad * 8);
#pragma unroll
            for (int nt = 0; nt < 4; nt++) {
                bf16x8 b = ((const bf16x8*)w2s)[(nt * 2 + ks) * 64 + lane];
                acc2[nt] = __builtin_amdgcn_mfma_f32_16x16x32_bf16(a, b, acc2[nt], 0, 0, 0);
            }
        }
#pragma unroll
        for (int r = 0; r < 4; r++) {
            int dest = edges[ebase + quad * 4 + r];
            if (mask[dest] != 0) {
                float* aggp = agg + dest * EH;
#pragma unroll
                for (int nt = 0; nt < 4; nt++) {
                    float x = acc2[nt][r] + b2v[nt];
                    atomicAdd(aggp + nt * 16 + col, silu_f(x) * C);
                }
            }
        }
        __syncthreads();
    }
}

// ---------------------------------------------------------------------------
// Node kernel: upd = silu([h_bf, agg] @ W1 + b1) @ W2 + b2; h += upd where mask.
// Zeroes agg rows after reading. fuse_out=1: also out = h_final @ W_out + b_out.
// ---------------------------------------------------------------------------
__global__ __launch_bounds__(256) void node_kernel(
    float* __restrict__ h, bf16_t* __restrict__ h_bf,
    float* __restrict__ agg, const int* __restrict__ mask,
    const bf16_t* __restrict__ w1p, const float* __restrict__ b1,
    const bf16_t* __restrict__ w2p, const float* __restrict__ b2, int zero_agg,
    const bf16_t* __restrict__ wop, const float* __restrict__ bo,
    float* __restrict__ out, int fuse_out)
{
    __shared__ __align__(16) bf16_t hl[4][16 * 136];
    int t = threadIdx.x, wave = t >> 6, lane = t & 63;
    int quad = lane >> 4, col = lane & 15;
    int m0 = blockIdx.x * 64 + wave * 16;
    int ndc = min(m0 + col, N_NODES - 1);

    floatx4 acc[8] = {};
#pragma unroll
    for (int ks = 0; ks < 6; ks++) {
        bf16x8 a;
        if (ks < 4) {
            a = *(const bf16x8*)(h_bf + ndc * HID + ks * 32 + quad * 8);
        } else {
            const float* ap = agg + ndc * EH + (ks - 4) * 32 + quad * 8;
            floatx4 f0 = *(const floatx4*)ap;
            floatx4 f1 = *(const floatx4*)(ap + 4);
#pragma unroll
            for (int j = 0; j < 4; j++) { a[j] = (bf16_t)f0[j]; a[j + 4] = (bf16_t)f1[j]; }
        }
#pragma unroll
        for (int nt = 0; nt < 8; nt++) {
            bf16x8 b = ((const bf16x8*)w1p)[(nt * 6 + ks) * 64 + lane];
            acc[nt] = __builtin_amdgcn_mfma_f32_16x16x32_bf16(a, b, acc[nt], 0, 0, 0);
        }
    }
    if (zero_agg && (m0 + col) < N_NODES) {
        floatx4 z = {0.0f, 0.0f, 0.0f, 0.0f};
        float* zp = agg + ndc * EH + quad * 8;
        *(floatx4*)zp = z; *(floatx4*)(zp + 4) = z;
        *(floatx4*)(zp + 32) = z; *(floatx4*)(zp + 36) = z;
    }
    bf16_t* myhl = hl[wave];
#pragma unroll
    for (int nt = 0; nt < 8; nt++)
#pragma unroll
        for (int r = 0; r < 4; r++) {
            float x = acc[nt][r] + b1[nt * 16 + col];
            myhl[(quad * 4 + r) * 136 + nt * 16 + col] = (bf16_t)silu_f(x);
        }
    // no barrier: myhl is wave-local, DS ops are in-order per wave

    floatx4 acc2[8] = {};
#pragma unroll
    for (int ks = 0; ks < 4; ks++) {
        bf16x8 a = *(const bf16x8*)(myhl + col * 136 + ks * 32 + quad * 8);
#pragma unroll
        for (int nt = 0; nt < 8; nt++) {
            bf16x8 b = ((const bf16x8*)w2p)[(nt * 4 + ks) * 64 + lane];
            acc2[nt] = __builtin_amdgcn_mfma_f32_16x16x32_bf16(a, b, acc2[nt], 0, 0, 0);
        }
    }
#pragma unroll
    for (int r = 0; r < 4; r++) {
        int nd2 = m0 + quad * 4 + r;
        bool valid = nd2 < N_NODES;
        bool upd = valid && mask[min(nd2, N_NODES - 1)] != 0;
        if (upd) {
#pragma unroll
            for (int nt = 0; nt < 8; nt++) {
                int n = nt * 16 + col;
                float hv = h[nd2 * HID + n] + acc2[nt][r] + b2[n];
                h[nd2 * HID + n] = hv;
                bf16_t hb = (bf16_t)hv;
                h_bf[nd2 * HID + n] = hb;
                if (fuse_out) myhl[(quad * 4 + r) * 136 + n] = hb;
            }
        } else if (fuse_out) {
#pragma unroll
            for (int nt = 0; nt < 8; nt++) {
                int n = nt * 16 + col;
                myhl[(quad * 4 + r) * 136 + n] =
                    valid ? h_bf[nd2 * HID + n] : (bf16_t)0.0f;
            }
        }
    }
    if (fuse_out) {
        floatx4 ao[4] = {};
#pragma unroll
        for (int ks = 0; ks < 4; ks++) {
            bf16x8 a = *(const bf16x8*)(myhl + col * 136 + ks * 32 + quad * 8);
#pragma unroll
            for (int nt = 0; nt < 4; nt++) {
                bf16x8 b = ((const bf16x8*)wop)[(nt * 4 + ks) * 64 + lane];
                ao[nt] = __builtin_amdgcn_mfma_f32_16x16x32_bf16(a, b, ao[nt], 0, 0, 0);
            }
        }
#pragma unroll
        for (int r = 0; r < 4; r++) {
            int nd2 = m0 + quad * 4 + r;
            if (nd2 < N_NODES) {
#pragma unroll
                for (int nt = 0; nt < 4; nt++) {
                    int n = nt * 16 + col;
                    out[nd2 * 64 + n] = ao[nt][r] + bo[n];
                }
            }
        }
    }
}

extern "C" void kernel_launch(void* const* d_in, const int* in_sizes, int n_in,
                              void* d_out, int out_size, void* d_ws, size_t ws_size,
                              hipStream_t stream) {
    const float* h0        = (const float*)d_in[0];
    const int*   edges_a   = (const int*)d_in[1];
    const int*   edges_b   = (const int*)d_in[2];
    const int*   mask_a    = (const int*)d_in[3];
    const int*   mask_b    = (const int*)d_in[4];
    const float* emb_in_w  = (const float*)d_in[5];
    const float* emb_in_b  = (const float*)d_in[6];
    const float* emb_out_w = (const float*)d_in[7];
    const float* emb_out_b = (const float*)d_in[8];
    const float* ew1 = (const float*)d_in[9];
    const float* eb1 = (const float*)d_in[10];
    const float* ew2 = (const float*)d_in[11];
    const float* eb2 = (const float*)d_in[12];
    const float* nw1 = (const float*)d_in[13];
    const float* nb1 = (const float*)d_in[14];
    const float* nw2 = (const float*)d_in[15];
    const float* nb2 = (const float*)d_in[16];

    const size_t SZ_H = 25600000, SZ_HBF = 12800000, SZ_AGG = 12800000, SZ_PK = 524288;
    const size_t SZ_S = 3200000, SZ_BINS = 200704, SZ_BS = 1024, SZ_CTR = 2048;

    char* ws = (char*)d_ws;
    size_t off = 0;
    float*  h    = (float*)(ws + off);  off += SZ_H;
    bf16_t* h_bf = (bf16_t*)(ws + off); off += SZ_HBF;
    float*  agg  = (float*)(ws + off);  off += SZ_AGG;
    bf16_t* pk   = (bf16_t*)(ws + off); off += SZ_PK;
    int* ssrc_a = (int*)(ws + off); off += SZ_S;
    int* sdst_a = (int*)(ws + off); off += SZ_S;
    int* ssrc_b = (int*)(ws + off); off += SZ_S;
    int* sdst_b = (int*)(ws + off); off += SZ_S;
    // bins_a..ctrs contiguous -> one memset
    int* bins_a = (int*)(ws + off); off += SZ_BINS;
    int* bins_b = (int*)(ws + off); off += SZ_BINS;
    int* bs_a   = (int*)(ws + off); off += SZ_BS;
    int* bs_b   = (int*)(ws + off); off += SZ_BS;
    int* ctrs   = (int*)(ws + off); off += SZ_CTR;   // 4 layers x 8 parts x 16 ints
    bool sorted_path = (ws_size >= off);

    bf16_t* pk_embin  = pk;
    bf16_t* pk_embout = pk + 8192;
    bf16_t* pk_ew1    = pk + 16384;
    bf16_t* pk_ew2    = pk + 81920;
    bf16_t* pk_nw1    = pk + 98304;
    bf16_t* pk_nw2    = pk + 196608;

    pack_all_kernel<<<128, 256, 0, stream>>>(emb_in_w, emb_out_w, ew1, ew2, nw1, nw2, pk);

    const int edge_grid = (N_EDGES + 255) / 256;  // 3125
    if (sorted_path) {
        hipMemsetAsync(bins_a, 0, 2 * SZ_BINS + 2 * SZ_BS + SZ_CTR, stream);
        hist2_kernel<<<2 * edge_grid, 256, 0, stream>>>(edges_a, edges_b, mask_a, mask_b,
                                                        bins_a, bins_b);
        scan_phase1<<<dim3(NCH, 2), 256, 0, stream>>>(bins_a, bins_b, bs_a, bs_b);
        scan_phase2<<<2, 256, 0, stream>>>(bs_a, bs_b, bins_a, bins_b);
        scan_phase3<<<dim3(NCH, 2), 256, 0, stream>>>(bins_a, bins_b, bs_a, bs_b);
        fill_src_kernel<<<dim3(NCH, 2), 256, 0, stream>>>(bins_a, bins_b, ssrc_a, ssrc_b);
        scatter2_kernel<<<2 * edge_grid, 256, 0, stream>>>(edges_a, edges_b, mask_a, mask_b,
                                                           bins_a, bins_b, sdst_a, sdst_b);
    }

    const int node_blocks = (N_NODES + 63) / 64;  // 782
    hipMemsetAsync(agg, 0, (size_t)N_NODES * EH * 4, stream);  // once; node zeroes after
    emb_in_kernel<<<node_blocks, 256, 0, stream>>>(h0, pk_embin, emb_in_b, h, h_bf);

    for (int l = 0; l < 4; l++) {
        const int* mask = (l & 1) ? mask_b : mask_a;
        float C = (l & 1) ? 0.03125f : 1.0f;
        if (sorted_path) {
            const int* ssrc = (l & 1) ? ssrc_b : ssrc_a;
            const int* sdst = (l & 1) ? sdst_b : sdst_a;
            const int* mp   = ((l & 1) ? bins_b : bins_a) + N_NODES;
            edge_kernel_sorted<<<768, 256, 0, stream>>>(h_bf, ssrc, sdst, mp,
                                                        pk_ew1 + l * 16384, eb1 + l * 64,
                                                        pk_ew2 + l * 4096,  eb2 + l * 64,
                                                        agg, C, ctrs + l * 128);
        } else {
            const int* edges = (l & 1) ? edges_b : edges_a;
            edge_kernel<<<768, 256, 0, stream>>>(h_bf, edges, mask,
                                                 pk_ew1 + l * 16384, eb1 + l * 64,
                                                 pk_ew2 + l * 4096,  eb2 + l * 64,
                                                 agg, C);
        }
        node_kernel<<<node_blocks, 256, 0, stream>>>(h, h_bf, agg, mask,
                                                     pk_nw1 + l * 24576, nb1 + l * 128,
                                                     pk_nw2 + l * 16384, nb2 + l * 128,
                                                     (l < 3) ? 1 : 0,
                                                     pk_embout, emb_out_b,
                                                     (float*)d_out, (l == 3) ? 1 : 0);
    }
}

// Round 12
// 479.747 us; speedup vs baseline: 1.1807x; 1.1807x over previous
//
#include <hip/hip_runtime.h>
#include <cstdint>

typedef __bf16 bf16_t;
typedef bf16_t bf16x8 __attribute__((ext_vector_type(8)));
typedef float floatx4 __attribute__((ext_vector_type(4)));
typedef unsigned short ushort4v __attribute__((ext_vector_type(4)));

constexpr int N_NODES = 50000;
constexpr int N_EDGES = 800000;
constexpr int HID = 128;
constexpr int EH = 64;
constexpr int NCH = (N_NODES + 255) / 256;  // 196 scan chunks

__device__ __forceinline__ float silu_f(float x) {
    return x * __builtin_amdgcn_rcpf(1.0f + __expf(-x));
}

// ---------------------------------------------------------------------------
// Fused weight pack: all 6 weight tensors -> bf16 MFMA B-fragment order.
// ---------------------------------------------------------------------------
__global__ __launch_bounds__(256) void pack_all_kernel(
    const float* __restrict__ embin, const float* __restrict__ embout,
    const float* __restrict__ ew1, const float* __restrict__ ew2,
    const float* __restrict__ nw1, const float* __restrict__ nw2,
    bf16_t* __restrict__ pk)
{
    int t = blockIdx.x * 256 + threadIdx.x;
    const float* W; int K, Nc; int base; bf16_t* out;
    if (t < 1024)       { W = embin;  K = 64;  Nc = 128; base = 0;     out = pk; }
    else if (t < 2048)  { W = embout; K = 128; Nc = 64;  base = 1024;  out = pk + 8192; }
    else if (t < 10240) { W = ew1;    K = 256; Nc = 64;  base = 2048;  out = pk + 16384; }
    else if (t < 12288) { W = ew2;    K = 64;  Nc = 64;  base = 10240; out = pk + 81920; }
    else if (t < 24576) { W = nw1;    K = 192; Nc = 128; base = 12288; out = pk + 98304; }
    else                { W = nw2;    K = 128; Nc = 128; base = 24576; out = pk + 196608; }
    t -= base;
    int KS = K >> 5, NT = Nc >> 4;
    int lane = t & 63;
    int chunk = t >> 6;
    int ks = chunk % KS;
    int nt = (chunk / KS) % NT;
    int l  = chunk / (KS * NT);
    int quad = lane >> 4, coln = lane & 15;
    const float* Wl = W + l * K * Nc;
    bf16x8 v;
#pragma unroll
    for (int j = 0; j < 8; j++)
        v[j] = (bf16_t)Wl[(ks * 32 + quad * 8 + j) * Nc + nt * 16 + coln];
    *(bf16x8*)(out + t * 8) = v;
}

// ---------------------------------------------------------------------------
// Counting sort of edges by destination (row), masked dests only.
// ---------------------------------------------------------------------------
__global__ void hist2_kernel(const int* __restrict__ ea, const int* __restrict__ eb,
                             const int* __restrict__ ma, const int* __restrict__ mb,
                             int* __restrict__ ba, int* __restrict__ bb) {
    int half = gridDim.x >> 1;
    int b = blockIdx.x;
    const int* erows; const int* mask; int* bins;
    if (b < half) { erows = ea; mask = ma; bins = ba; }
    else          { erows = eb; mask = mb; bins = bb; b -= half; }
    int i = b * 256 + threadIdx.x;
    if (i >= N_EDGES) return;
    int r = erows[i];
    if (mask[r] != 0) atomicAdd(&bins[r], 1);
}

__global__ __launch_bounds__(256) void scan_phase1(
    const int* __restrict__ bins_a, const int* __restrict__ bins_b,
    int* __restrict__ bs_a, int* __restrict__ bs_b) {
    const int* bins = blockIdx.y ? bins_b : bins_a;
    int* bs = blockIdx.y ? bs_b : bs_a;
    int i = blockIdx.x * 256 + threadIdx.x;
    int v = (i < N_NODES) ? bins[i] : 0;
#pragma unroll
    for (int off = 32; off; off >>= 1) v += __shfl_down(v, off, 64);
    __shared__ int ws_[4];
    int lane = threadIdx.x & 63, wv = threadIdx.x >> 6;
    if (lane == 0) ws_[wv] = v;
    __syncthreads();
    if (threadIdx.x == 0) bs[blockIdx.x] = ws_[0] + ws_[1] + ws_[2] + ws_[3];
}

__global__ __launch_bounds__(256) void scan_phase2(
    int* __restrict__ bs_a, int* __restrict__ bs_b,
    int* __restrict__ bins_a, int* __restrict__ bins_b) {
    int* bs = blockIdx.x ? bs_b : bs_a;
    int* bins = blockIdx.x ? bins_b : bins_a;
    int t = threadIdx.x, lane = t & 63, wv = t >> 6;
    int v = (t < NCH) ? bs[t] : 0;
    int s = v;
#pragma unroll
    for (int off = 1; off < 64; off <<= 1) {
        int u = __shfl_up(s, off, 64);
        if (lane >= off) s += u;
    }
    __shared__ int wsum[4];
    if (lane == 63) wsum[wv] = s;
    __syncthreads();
    int woff = 0;
    for (int w = 0; w < wv; w++) woff += wsum[w];
    int excl = s - v + woff;
    if (t < NCH) bs[t] = excl;
    if (t == NCH - 1) bins[N_NODES] = excl + v;  // total kept-edge count M
}

__global__ __launch_bounds__(256) void scan_phase3(
    int* __restrict__ bins_a, int* __restrict__ bins_b,
    const int* __restrict__ bs_a, const int* __restrict__ bs_b) {
    int* bins = blockIdx.y ? bins_b : bins_a;
    const int* bs = blockIdx.y ? bs_b : bs_a;
    int i = blockIdx.x * 256 + threadIdx.x;
    int t = threadIdx.x, lane = t & 63, wv = t >> 6;
    int v = (i < N_NODES) ? bins[i] : 0;
    int s = v;
#pragma unroll
    for (int off = 1; off < 64; off <<= 1) {
        int u = __shfl_up(s, off, 64);
        if (lane >= off) s += u;
    }
    __shared__ int wsum[4];
    if (lane == 63) wsum[wv] = s;
    __syncthreads();
    int woff = 0;
    for (int w = 0; w < wv; w++) woff += wsum[w];
    if (i < N_NODES) bins[i] = s - v + woff + bs[blockIdx.x];
}

// src reconstruction: node r owns [bins[r], bins[r+1]) — dense sequential fill.
// MUST run before scatter2 (which mutates bins).
__global__ void fill_src_kernel(const int* __restrict__ bins_a, const int* __restrict__ bins_b,
                                int* __restrict__ ssrc_a, int* __restrict__ ssrc_b) {
    const int* bins = blockIdx.y ? bins_b : bins_a;
    int* ssrc = blockIdx.y ? ssrc_b : ssrc_a;
    int r = blockIdx.x * 256 + threadIdx.x;
    if (r >= N_NODES) return;
    int p0 = bins[r], p1 = bins[r + 1];
    for (int p = p0; p < p1; p++) ssrc[p] = r;
}

// scatter: only the dst column (4B) goes through the random-position store
__global__ void scatter2_kernel(const int* __restrict__ ea, const int* __restrict__ eb,
                                const int* __restrict__ ma, const int* __restrict__ mb,
                                int* __restrict__ ba, int* __restrict__ bb,
                                int* __restrict__ sdst_a, int* __restrict__ sdst_b) {
    int half = gridDim.x >> 1;
    int b = blockIdx.x;
    const int* e; const int* mask; int* bins; int* sdst;
    if (b < half) { e = ea; mask = ma; bins = ba; sdst = sdst_a; }
    else          { e = eb; mask = mb; bins = bb; sdst = sdst_b; b -= half; }
    int i = b * 256 + threadIdx.x;
    if (i >= N_EDGES) return;
    int r = e[i];
    if (mask[r] == 0) return;
    int c = e[N_EDGES + i];
    int pos = atomicAdd(&bins[r], 1);
    sdst[pos] = c;
}

// ---------------------------------------------------------------------------
// emb_in: h0[N,64] @ W[64,128] + b -> h (fp32) and h_bf (bf16)
// ---------------------------------------------------------------------------
__global__ __launch_bounds__(256) void emb_in_kernel(
    const float* __restrict__ h0, const bf16_t* __restrict__ wp,
    const float* __restrict__ bias, float* __restrict__ h, bf16_t* __restrict__ h_bf)
{
    int t = threadIdx.x, wave = t >> 6, lane = t & 63;
    int quad = lane >> 4, col = lane & 15;
    int m0 = blockIdx.x * 64 + wave * 16;
    int ndc = min(m0 + col, N_NODES - 1);
    floatx4 acc[8] = {};
#pragma unroll
    for (int ks = 0; ks < 2; ks++) {
        const float* ap = h0 + ndc * 64 + ks * 32 + quad * 8;
        floatx4 f0 = *(const floatx4*)ap;
        floatx4 f1 = *(const floatx4*)(ap + 4);
        bf16x8 a;
#pragma unroll
        for (int j = 0; j < 4; j++) { a[j] = (bf16_t)f0[j]; a[j + 4] = (bf16_t)f1[j]; }
#pragma unroll
        for (int nt = 0; nt < 8; nt++) {
            bf16x8 b = ((const bf16x8*)wp)[(nt * 2 + ks) * 64 + lane];
            acc[nt] = __builtin_amdgcn_mfma_f32_16x16x32_bf16(a, b, acc[nt], 0, 0, 0);
        }
    }
#pragma unroll
    for (int r = 0; r < 4; r++) {
        int nd2 = m0 + quad * 4 + r;
        if (nd2 < N_NODES) {
#pragma unroll
            for (int nt = 0; nt < 8; nt++) {
                int n = nt * 16 + col;
                float x = acc[nt][r] + bias[n];
                h[nd2 * HID + n] = x;
                h_bf[nd2 * HID + n] = (bf16_t)x;
            }
        }
    }
}

// ---------------------------------------------------------------------------
// Sorted edge kernel v8: round-10 structure (static grid-stride tiles,
// prefetch pipeline, mbT-transposed combine) with split ssrc/sdst inputs.
// ---------------------------------------------------------------------------
__global__ __launch_bounds__(256, 3) void edge_kernel_sorted(
    const bf16_t* __restrict__ h_bf, const int* __restrict__ ssrc,
    const int* __restrict__ sdst, const int* __restrict__ m_ptr,
    const bf16_t* __restrict__ w1p, const float* __restrict__ b1,
    const bf16_t* __restrict__ w2p, const float* __restrict__ b2,
    float* __restrict__ agg, float C)
{
    __shared__ __align__(16) bf16_t w1s[16384];        // 32 KB GEMM1 B-frags
    __shared__ __align__(16) bf16_t pool[4][64 * 40];  // per-wave hl/mbT union

    int t = threadIdx.x;
#pragma unroll
    for (int i = 0; i < 8; i++)
        ((bf16x8*)w1s)[t + 256 * i] = ((const bf16x8*)w1p)[t + 256 * i];
    __syncthreads();  // once

    int wave = t >> 6, lane = t & 63, quad = lane >> 4, col = lane & 15;
    bf16_t* hl = pool[wave];   // GEMM1->GEMM2 transpose, stride 72
    bf16_t* mbT = pool[wave];  // messages transposed [n][e], stride 40

    float b1v[4], b2v[4];
#pragma unroll
    for (int nt = 0; nt < 4; nt++) { b1v[nt] = b1[nt * 16 + col]; b2v[nt] = b2[nt * 16 + col]; }

    int M = m_ptr[0];
    int ntiles = (M + 31) >> 5;
    int wid = blockIdx.x * 4 + wave, nw = gridDim.x * 4;
    if (wid >= ntiles) return;

    // prologue: load tile wid's edges + gather its A-frags
    int sr = 0x7fffffff, ds = 0x7fffffff;
    { int p = wid * 32 + lane; if (lane < 32 && p < M) { sr = ssrc[p]; ds = sdst[p]; } }
    bf16x8 a[2][8];
    {
        int ns0 = min(__shfl(sr, col, 64), N_NODES - 1);
        int ns1 = min(__shfl(sr, 16 + col, 64), N_NODES - 1);
        int nd0 = min(__shfl(ds, col, 64), N_NODES - 1);
        int nd1 = min(__shfl(ds, 16 + col, 64), N_NODES - 1);
#pragma unroll
        for (int ks = 0; ks < 8; ks++) {
            int o = (ks & 3) * 32 + quad * 8;
            a[0][ks] = *(const bf16x8*)(h_bf + (ks < 4 ? ns0 : nd0) * HID + o);
            a[1][ks] = *(const bf16x8*)(h_bf + (ks < 4 ? ns1 : nd1) * HID + o);
        }
    }

    for (int tile = wid; tile < ntiles; tile += nw) {
        // prefetch next tile's edge columns
        int tnc = min(tile + nw, ntiles - 1);
        int srn = 0x7fffffff, dsn = 0x7fffffff;
        { int p = tnc * 32 + lane; if (lane < 32 && p < M) { srn = ssrc[p]; dsn = sdst[p]; } }

        // GEMM1
        floatx4 acc[2][4] = {};
#pragma unroll
        for (int ks = 0; ks < 8; ks++) {
#pragma unroll
            for (int nt = 0; nt < 4; nt++) {
                bf16x8 b = ((const bf16x8*)w1s)[(nt * 8 + ks) * 64 + lane];
                acc[0][nt] = __builtin_amdgcn_mfma_f32_16x16x32_bf16(a[0][ks], b, acc[0][nt], 0, 0, 0);
                acc[1][nt] = __builtin_amdgcn_mfma_f32_16x16x32_bf16(a[1][ks], b, acc[1][nt], 0, 0, 0);
            }
        }

        // next tile's gathers — in flight under epilogues/GEMM2
        bf16x8 an[2][8];
        {
            int ns0 = min(__shfl(srn, col, 64), N_NODES - 1);
            int ns1 = min(__shfl(srn, 16 + col, 64), N_NODES - 1);
            int nd0 = min(__shfl(dsn, col, 64), N_NODES - 1);
            int nd1 = min(__shfl(dsn, 16 + col, 64), N_NODES - 1);
#pragma unroll
            for (int ks = 0; ks < 8; ks++) {
                int o = (ks & 3) * 32 + quad * 8;
                an[0][ks] = *(const bf16x8*)(h_bf + (ks < 4 ? ns0 : nd0) * HID + o);
                an[1][ks] = *(const bf16x8*)(h_bf + (ks < 4 ? ns1 : nd1) * HID + o);
            }
        }

        // epilogue1: C-layout -> A-layout (wave-local LDS, stride 72)
#pragma unroll
        for (int m = 0; m < 2; m++)
#pragma unroll
            for (int nt = 0; nt < 4; nt++)
#pragma unroll
                for (int r = 0; r < 4; r++)
                    hl[(m * 16 + quad * 4 + r) * 72 + nt * 16 + col] =
                        (bf16_t)silu_f(acc[m][nt][r] + b1v[nt]);

        floatx4 acc2[2][4] = {};
#pragma unroll
        for (int ks = 0; ks < 2; ks++) {
            bf16x8 a2[2];
#pragma unroll
            for (int m = 0; m < 2; m++)
                a2[m] = *(const bf16x8*)(hl + (m * 16 + col) * 72 + ks * 32 + quad * 8);
#pragma unroll
            for (int nt = 0; nt < 4; nt++) {
                bf16x8 b = ((const bf16x8*)w2p)[(nt * 2 + ks) * 64 + lane];
                acc2[0][nt] = __builtin_amdgcn_mfma_f32_16x16x32_bf16(a2[0], b, acc2[0][nt], 0, 0, 0);
                acc2[1][nt] = __builtin_amdgcn_mfma_f32_16x16x32_bf16(a2[1], b, acc2[1][nt], 0, 0, 0);
            }
        }
        // epilogue2: messages TRANSPOSED mbT[n][e], 4 r-values per b64 write
#pragma unroll
        for (int m = 0; m < 2; m++)
#pragma unroll
            for (int nt = 0; nt < 4; nt++) {
                ushort4v p;
#pragma unroll
                for (int r = 0; r < 4; r++) {
                    bf16_t bv = (bf16_t)(silu_f(acc2[m][nt][r] + b2v[nt]) * C);
                    p[r] = __builtin_bit_cast(unsigned short, bv);
                }
                *(ushort4v*)(mbT + (nt * 16 + col) * 40 + m * 16 + quad * 4) = p;
            }

        // combine: preload full column, then pure-VALU run-length scan
        {
            float mv[32];
#pragma unroll
            for (int i = 0; i < 4; i++) {
                bf16x8 v8 = *(const bf16x8*)(mbT + lane * 40 + i * 8);
#pragma unroll
                for (int j = 0; j < 8; j++) mv[i * 8 + j] = (float)v8[j];
            }
            int dp = __shfl(sr, 0, 64);
            float run = mv[0];
#pragma unroll
            for (int r = 1; r < 32; r++) {
                int d = __shfl(sr, r, 64);
                if (d != dp) {  // wave-uniform: coalesced atomic bursts
                    if (dp < N_NODES) atomicAdd(agg + dp * EH + lane, run);
                    run = mv[r]; dp = d;
                } else run += mv[r];
            }
            if (dp < N_NODES) atomicAdd(agg + dp * EH + lane, run);
        }

        // rotate prefetched state
        sr = srn; ds = dsn;
#pragma unroll
        for (int m = 0; m < 2; m++)
#pragma unroll
            for (int ks = 0; ks < 8; ks++) a[m][ks] = an[m][ks];
    }
}

// ---------------------------------------------------------------------------
// Fallback (unsorted) edge kernel — used only if ws_size is too small.
// ---------------------------------------------------------------------------
__global__ __launch_bounds__(256) void edge_kernel(
    const bf16_t* __restrict__ h_bf, const int* __restrict__ edges,
    const int* __restrict__ mask,
    const bf16_t* __restrict__ w1p, const float* __restrict__ b1,
    const bf16_t* __restrict__ w2p, const float* __restrict__ b2,
    float* __restrict__ agg, float C)
{
    __shared__ __align__(16) bf16_t w1s[16384];
    __shared__ __align__(16) bf16_t w2s[4096];
    __shared__ __align__(16) bf16_t hl[4][16 * 72];

    int t = threadIdx.x;
#pragma unroll
    for (int i = 0; i < 8; i++)
        ((bf16x8*)w1s)[t + 256 * i] = ((const bf16x8*)w1p)[t + 256 * i];
#pragma unroll
    for (int i = 0; i < 2; i++)
        ((bf16x8*)w2s)[t + 256 * i] = ((const bf16x8*)w2p)[t + 256 * i];
    __syncthreads();

    int wave = t >> 6, lane = t & 63, quad = lane >> 4, col = lane & 15;
    bf16_t* myhl = hl[wave];

    float b1v[4], b2v[4];
#pragma unroll
    for (int nt = 0; nt < 4; nt++) { b1v[nt] = b1[nt * 16 + col]; b2v[nt] = b2[nt * 16 + col]; }

    const int ntile_cnt = N_EDGES / 64;
    for (int tile = blockIdx.x; tile < ntile_cnt; tile += gridDim.x) {
        int ebase = tile * 64 + wave * 16;
        int src = edges[ebase + col];
        int dst = edges[N_EDGES + ebase + col];

        floatx4 acc[4] = {};
#pragma unroll
        for (int ks = 0; ks < 8; ks++) {
            int idx = (ks < 4) ? src : dst;
            bf16x8 a = *(const bf16x8*)(h_bf + idx * HID + (ks & 3) * 32 + quad * 8);
#pragma unroll
            for (int nt = 0; nt < 4; nt++) {
                bf16x8 b = ((const bf16x8*)w1s)[(nt * 8 + ks) * 64 + lane];
                acc[nt] = __builtin_amdgcn_mfma_f32_16x16x32_bf16(a, b, acc[nt], 0, 0, 0);
            }
        }
#pragma unroll
        for (int nt = 0; nt < 4; nt++)
#pragma unroll
            for (int r = 0; r < 4; r++)
                myhl[(quad * 4 + r) * 72 + nt * 16 + col] = (bf16_t)silu_f(acc[nt][r] + b1v[nt]);
        __syncthreads();

        floatx4 acc2[4] = {};
#pragma unroll
        for (int ks = 0; ks < 2; ks++) {
            bf16x8 a = *(const bf16x8*)(myhl + col * 72 + ks * 32 + quad * 8);
#pragma unroll
            for (int nt = 0; nt < 4; nt++) {
                bf16x8 b = ((const bf16x8*)w2s)[(nt * 2 + ks) * 64 + lane];
                acc2[nt] = __builtin_amdgcn_mfma_f32_16x16x32_bf16(a, b, acc2[nt], 0, 0, 0);
            }
        }
#pragma unroll
        for (int r = 0; r < 4; r++) {
            int dest = edges[ebase + quad * 4 + r];
            if (mask[dest] != 0) {
                float* aggp = agg + dest * EH;
#pragma unroll
                for (int nt = 0; nt < 4; nt++) {
                    float x = acc2[nt][r] + b2v[nt];
                    atomicAdd(aggp + nt * 16 + col, silu_f(x) * C);
                }
            }
        }
        __syncthreads();
    }
}

// ---------------------------------------------------------------------------
// Node kernel: upd = silu([h_bf, agg] @ W1 + b1) @ W2 + b2; h += upd where mask.
// Zeroes agg rows after reading. fuse_out=1: also out = h_final @ W_out + b_out.
// ---------------------------------------------------------------------------
__global__ __launch_bounds__(256) void node_kernel(
    float* __restrict__ h, bf16_t* __restrict__ h_bf,
    float* __restrict__ agg, const int* __restrict__ mask,
    const bf16_t* __restrict__ w1p, const float* __restrict__ b1,
    const bf16_t* __restrict__ w2p, const float* __restrict__ b2, int zero_agg,
    const bf16_t* __restrict__ wop, const float* __restrict__ bo,
    float* __restrict__ out, int fuse_out)
{
    __shared__ __align__(16) bf16_t hl[4][16 * 136];
    int t = threadIdx.x, wave = t >> 6, lane = t & 63;
    int quad = lane >> 4, col = lane & 15;
    int m0 = blockIdx.x * 64 + wave * 16;
    int ndc = min(m0 + col, N_NODES - 1);

    floatx4 acc[8] = {};
#pragma unroll
    for (int ks = 0; ks < 6; ks++) {
        bf16x8 a;
        if (ks < 4) {
            a = *(const bf16x8*)(h_bf + ndc * HID + ks * 32 + quad * 8);
        } else {
            const float* ap = agg + ndc * EH + (ks - 4) * 32 + quad * 8;
            floatx4 f0 = *(const floatx4*)ap;
            floatx4 f1 = *(const floatx4*)(ap + 4);
#pragma unroll
            for (int j = 0; j < 4; j++) { a[j] = (bf16_t)f0[j]; a[j + 4] = (bf16_t)f1[j]; }
        }
#pragma unroll
        for (int nt = 0; nt < 8; nt++) {
            bf16x8 b = ((const bf16x8*)w1p)[(nt * 6 + ks) * 64 + lane];
            acc[nt] = __builtin_amdgcn_mfma_f32_16x16x32_bf16(a, b, acc[nt], 0, 0, 0);
        }
    }
    if (zero_agg && (m0 + col) < N_NODES) {
        floatx4 z = {0.0f, 0.0f, 0.0f, 0.0f};
        float* zp = agg + ndc * EH + quad * 8;
        *(floatx4*)zp = z; *(floatx4*)(zp + 4) = z;
        *(floatx4*)(zp + 32) = z; *(floatx4*)(zp + 36) = z;
    }
    bf16_t* myhl = hl[wave];
#pragma unroll
    for (int nt = 0; nt < 8; nt++)
#pragma unroll
        for (int r = 0; r < 4; r++) {
            float x = acc[nt][r] + b1[nt * 16 + col];
            myhl[(quad * 4 + r) * 136 + nt * 16 + col] = (bf16_t)silu_f(x);
        }
    // no barrier: myhl is wave-local, DS ops are in-order per wave

    floatx4 acc2[8] = {};
#pragma unroll
    for (int ks = 0; ks < 4; ks++) {
        bf16x8 a = *(const bf16x8*)(myhl + col * 136 + ks * 32 + quad * 8);
#pragma unroll
        for (int nt = 0; nt < 8; nt++) {
            bf16x8 b = ((const bf16x8*)w2p)[(nt * 4 + ks) * 64 + lane];
            acc2[nt] = __builtin_amdgcn_mfma_f32_16x16x32_bf16(a, b, acc2[nt], 0, 0, 0);
        }
    }
#pragma unroll
    for (int r = 0; r < 4; r++) {
        int nd2 = m0 + quad * 4 + r;
        bool valid = nd2 < N_NODES;
        bool upd = valid && mask[min(nd2, N_NODES - 1)] != 0;
        if (upd) {
#pragma unroll
            for (int nt = 0; nt < 8; nt++) {
                int n = nt * 16 + col;
                float hv = h[nd2 * HID + n] + acc2[nt][r] + b2[n];
                h[nd2 * HID + n] = hv;
                bf16_t hb = (bf16_t)hv;
                h_bf[nd2 * HID + n] = hb;
                if (fuse_out) myhl[(quad * 4 + r) * 136 + n] = hb;
            }
        } else if (fuse_out) {
#pragma unroll
            for (int nt = 0; nt < 8; nt++) {
                int n = nt * 16 + col;
                myhl[(quad * 4 + r) * 136 + n] =
                    valid ? h_bf[nd2 * HID + n] : (bf16_t)0.0f;
            }
        }
    }
    if (fuse_out) {
        floatx4 ao[4] = {};
#pragma unroll
        for (int ks = 0; ks < 4; ks++) {
            bf16x8 a = *(const bf16x8*)(myhl + col * 136 + ks * 32 + quad * 8);
#pragma unroll
            for (int nt = 0; nt < 4; nt++) {
                bf16x8 b = ((const bf16x8*)wop)[(nt * 4 + ks) * 64 + lane];
                ao[nt] = __builtin_amdgcn_mfma_f32_16x16x32_bf16(a, b, ao[nt], 0, 0, 0);
            }
        }
#pragma unroll
        for (int r = 0; r < 4; r++) {
            int nd2 = m0 + quad * 4 + r;
            if (nd2 < N_NODES) {
#pragma unroll
                for (int nt = 0; nt < 4; nt++) {
                    int n = nt * 16 + col;
                    out[nd2 * 64 + n] = ao[nt][r] + bo[n];
                }
            }
        }
    }
}

extern "C" void kernel_launch(void* const* d_in, const int* in_sizes, int n_in,
                              void* d_out, int out_size, void* d_ws, size_t ws_size,
                              hipStream_t stream) {
    const float* h0        = (const float*)d_in[0];
    const int*   edges_a   = (const int*)d_in[1];
    const int*   edges_b   = (const int*)d_in[2];
    const int*   mask_a    = (const int*)d_in[3];
    const int*   mask_b    = (const int*)d_in[4];
    const float* emb_in_w  = (const float*)d_in[5];
    const float* emb_in_b  = (const float*)d_in[6];
    const float* emb_out_w = (const float*)d_in[7];
    const float* emb_out_b = (const float*)d_in[8];
    const float* ew1 = (const float*)d_in[9];
    const float* eb1 = (const float*)d_in[10];
    const float* ew2 = (const float*)d_in[11];
    const float* eb2 = (const float*)d_in[12];
    const float* nw1 = (const float*)d_in[13];
    const float* nb1 = (const float*)d_in[14];
    const float* nw2 = (const float*)d_in[15];
    const float* nb2 = (const float*)d_in[16];

    const size_t SZ_H = 25600000, SZ_HBF = 12800000, SZ_AGG = 12800000, SZ_PK = 524288;
    const size_t SZ_S = 3200000, SZ_BINS = 200704, SZ_BS = 1024;

    char* ws = (char*)d_ws;
    size_t off = 0;
    float*  h    = (float*)(ws + off);  off += SZ_H;
    bf16_t* h_bf = (bf16_t*)(ws + off); off += SZ_HBF;
    float*  agg  = (float*)(ws + off);  off += SZ_AGG;
    bf16_t* pk   = (bf16_t*)(ws + off); off += SZ_PK;
    int* ssrc_a = (int*)(ws + off); off += SZ_S;
    int* sdst_a = (int*)(ws + off); off += SZ_S;
    int* ssrc_b = (int*)(ws + off); off += SZ_S;
    int* sdst_b = (int*)(ws + off); off += SZ_S;
    int* bins_a = (int*)(ws + off); off += SZ_BINS;  // bins..bs contiguous -> one memset
    int* bins_b = (int*)(ws + off); off += SZ_BINS;
    int* bs_a   = (int*)(ws + off); off += SZ_BS;
    int* bs_b   = (int*)(ws + off); off += SZ_BS;
    bool sorted_path = (ws_size >= off);

    bf16_t* pk_embin  = pk;
    bf16_t* pk_embout = pk + 8192;
    bf16_t* pk_ew1    = pk + 16384;
    bf16_t* pk_ew2    = pk + 81920;
    bf16_t* pk_nw1    = pk + 98304;
    bf16_t* pk_nw2    = pk + 196608;

    pack_all_kernel<<<128, 256, 0, stream>>>(emb_in_w, emb_out_w, ew1, ew2, nw1, nw2, pk);

    const int edge_grid = (N_EDGES + 255) / 256;  // 3125
    if (sorted_path) {
        hipMemsetAsync(bins_a, 0, 2 * SZ_BINS + 2 * SZ_BS, stream);
        hist2_kernel<<<2 * edge_grid, 256, 0, stream>>>(edges_a, edges_b, mask_a, mask_b,
                                                        bins_a, bins_b);
        scan_phase1<<<dim3(NCH, 2), 256, 0, stream>>>(bins_a, bins_b, bs_a, bs_b);
        scan_phase2<<<2, 256, 0, stream>>>(bs_a, bs_b, bins_a, bins_b);
        scan_phase3<<<dim3(NCH, 2), 256, 0, stream>>>(bins_a, bins_b, bs_a, bs_b);
        fill_src_kernel<<<dim3(NCH, 2), 256, 0, stream>>>(bins_a, bins_b, ssrc_a, ssrc_b);
        scatter2_kernel<<<2 * edge_grid, 256, 0, stream>>>(edges_a, edges_b, mask_a, mask_b,
                                                           bins_a, bins_b, sdst_a, sdst_b);
    }

    const int node_blocks = (N_NODES + 63) / 64;  // 782
    hipMemsetAsync(agg, 0, (size_t)N_NODES * EH * 4, stream);  // once; node zeroes after
    emb_in_kernel<<<node_blocks, 256, 0, stream>>>(h0, pk_embin, emb_in_b, h, h_bf);

    for (int l = 0; l < 4; l++) {
        const int* mask = (l & 1) ? mask_b : mask_a;
        float C = (l & 1) ? 0.03125f : 1.0f;
        if (sorted_path) {
            const int* ssrc = (l & 1) ? ssrc_b : ssrc_a;
            const int* sdst = (l & 1) ? sdst_b : sdst_a;
            const int* mp   = ((l & 1) ? bins_b : bins_a) + N_NODES;
            edge_kernel_sorted<<<768, 256, 0, stream>>>(h_bf, ssrc, sdst, mp,
                                                        pk_ew1 + l * 16384, eb1 + l * 64,
                                                        pk_ew2 + l * 4096,  eb2 + l * 64,
                                                        agg, C);
        } else {
            const int* edges = (l & 1) ? edges_b : edges_a;
            edge_kernel<<<768, 256, 0, stream>>>(h_bf, edges, mask,
                                                 pk_ew1 + l * 16384, eb1 + l * 64,
                                                 pk_ew2 + l * 4096,  eb2 + l * 64,
                                                 agg, C);
        }
        node_kernel<<<node_blocks, 256, 0, stream>>>(h, h_bf, agg, mask,
                                                     pk_nw1 + l * 24576, nb1 + l * 128,
                                                     pk_nw2 + l * 16384, nb2 + l * 128,
                                                     (l < 3) ? 1 : 0,
                                                     pk_embout, emb_out_b,
                                                     (float*)d_out, (l == 3) ? 1 : 0);
    }
}

// Round 13
// 444.303 us; speedup vs baseline: 1.2749x; 1.0798x over previous
//
#include <hip/hip_runtime.h>
#include <cstdint>

typedef __bf16 bf16_t;
typedef bf16_t bf16x8 __attribute__((ext_vector_type(8)));
typedef float floatx4 __attribute__((ext_vector_type(4)));
typedef unsigned short ushort4v __attribute__((ext_vector_type(4)));

constexpr int N_NODES = 50000;
constexpr int N_EDGES = 800000;
constexpr int HID = 128;
constexpr int EH = 64;
constexpr int NCH = (N_NODES + 255) / 256;  // 196 scan chunks

__device__ __forceinline__ float silu_f(float x) {
    return x * __builtin_amdgcn_rcpf(1.0f + __expf(-x));
}

// ---------------------------------------------------------------------------
// Fused weight pack: all 6 weight tensors -> bf16 MFMA B-fragment order.
// ---------------------------------------------------------------------------
__global__ __launch_bounds__(256) void pack_all_kernel(
    const float* __restrict__ embin, const float* __restrict__ embout,
    const float* __restrict__ ew1, const float* __restrict__ ew2,
    const float* __restrict__ nw1, const float* __restrict__ nw2,
    bf16_t* __restrict__ pk)
{
    int t = blockIdx.x * 256 + threadIdx.x;
    const float* W; int K, Nc; int base; bf16_t* out;
    if (t < 1024)       { W = embin;  K = 64;  Nc = 128; base = 0;     out = pk; }
    else if (t < 2048)  { W = embout; K = 128; Nc = 64;  base = 1024;  out = pk + 8192; }
    else if (t < 10240) { W = ew1;    K = 256; Nc = 64;  base = 2048;  out = pk + 16384; }
    else if (t < 12288) { W = ew2;    K = 64;  Nc = 64;  base = 10240; out = pk + 81920; }
    else if (t < 24576) { W = nw1;    K = 192; Nc = 128; base = 12288; out = pk + 98304; }
    else                { W = nw2;    K = 128; Nc = 128; base = 24576; out = pk + 196608; }
    t -= base;
    int KS = K >> 5, NT = Nc >> 4;
    int lane = t & 63;
    int chunk = t >> 6;
    int ks = chunk % KS;
    int nt = (chunk / KS) % NT;
    int l  = chunk / (KS * NT);
    int quad = lane >> 4, coln = lane & 15;
    const float* Wl = W + l * K * Nc;
    bf16x8 v;
#pragma unroll
    for (int j = 0; j < 8; j++)
        v[j] = (bf16_t)Wl[(ks * 32 + quad * 8 + j) * Nc + nt * 16 + coln];
    *(bf16x8*)(out + t * 8) = v;
}

// ---------------------------------------------------------------------------
// Counting sort of edges by destination (row), masked dests only.
// ---------------------------------------------------------------------------
__global__ void hist2_kernel(const int* __restrict__ ea, const int* __restrict__ eb,
                             const int* __restrict__ ma, const int* __restrict__ mb,
                             int* __restrict__ ba, int* __restrict__ bb) {
    int half = gridDim.x >> 1;
    int b = blockIdx.x;
    const int* erows; const int* mask; int* bins;
    if (b < half) { erows = ea; mask = ma; bins = ba; }
    else          { erows = eb; mask = mb; bins = bb; b -= half; }
    int i = b * 256 + threadIdx.x;
    if (i >= N_EDGES) return;
    int r = erows[i];
    if (mask[r] != 0) atomicAdd(&bins[r], 1);
}

// per-256-chunk sums (also reused for mask compaction: bins := mask)
__global__ __launch_bounds__(256) void scan_phase1(
    const int* __restrict__ bins_a, const int* __restrict__ bins_b,
    int* __restrict__ bs_a, int* __restrict__ bs_b) {
    const int* bins = blockIdx.y ? bins_b : bins_a;
    int* bs = blockIdx.y ? bs_b : bs_a;
    int i = blockIdx.x * 256 + threadIdx.x;
    int v = (i < N_NODES) ? (bins[i] != 0 ? bins[i] : 0) : 0;
#pragma unroll
    for (int off = 32; off; off >>= 1) v += __shfl_down(v, off, 64);
    __shared__ int ws_[4];
    int lane = threadIdx.x & 63, wv = threadIdx.x >> 6;
    if (lane == 0) ws_[wv] = v;
    __syncthreads();
    if (threadIdx.x == 0) bs[blockIdx.x] = ws_[0] + ws_[1] + ws_[2] + ws_[3];
}

__global__ __launch_bounds__(256) void scan_phase2(
    int* __restrict__ bs_a, int* __restrict__ bs_b,
    int* __restrict__ bins_a, int* __restrict__ bins_b) {
    int* bs = blockIdx.x ? bs_b : bs_a;
    int* bins = blockIdx.x ? bins_b : bins_a;
    int t = threadIdx.x, lane = t & 63, wv = t >> 6;
    int v = (t < NCH) ? bs[t] : 0;
    int s = v;
#pragma unroll
    for (int off = 1; off < 64; off <<= 1) {
        int u = __shfl_up(s, off, 64);
        if (lane >= off) s += u;
    }
    __shared__ int wsum[4];
    if (lane == 63) wsum[wv] = s;
    __syncthreads();
    int woff = 0;
    for (int w = 0; w < wv; w++) woff += wsum[w];
    int excl = s - v + woff;
    if (t < NCH) bs[t] = excl;
    if (t == NCH - 1) bins[N_NODES] = excl + v;  // total kept-edge count M
}

// scan 196 mask-chunk sums in place; write total to cnt[0]
__global__ __launch_bounds__(256) void mask_scan2(
    int* __restrict__ ms_a, int* __restrict__ ms_b,
    int* __restrict__ cnt_a, int* __restrict__ cnt_b) {
    int* ms = blockIdx.x ? ms_b : ms_a;
    int* cnt = blockIdx.x ? cnt_b : cnt_a;
    int t = threadIdx.x, lane = t & 63, wv = t >> 6;
    int v = (t < NCH) ? ms[t] : 0;
    int s = v;
#pragma unroll
    for (int off = 1; off < 64; off <<= 1) {
        int u = __shfl_up(s, off, 64);
        if (lane >= off) s += u;
    }
    __shared__ int wsum[4];
    if (lane == 63) wsum[wv] = s;
    __syncthreads();
    int woff = 0;
    for (int w = 0; w < wv; w++) woff += wsum[w];
    int excl = s - v + woff;
    if (t < NCH) ms[t] = excl;
    if (t == NCH - 1) cnt[0] = excl + v;
}

// ballot-based masked-node compaction (list in ascending node order)
__global__ __launch_bounds__(256) void compact_kernel(
    const int* __restrict__ ma, const int* __restrict__ mb,
    const int* __restrict__ ms_a, const int* __restrict__ ms_b,
    int* __restrict__ la, int* __restrict__ lb) {
    const int* mask = blockIdx.y ? mb : ma;
    const int* ms = blockIdx.y ? ms_b : ms_a;
    int* list = blockIdx.y ? lb : la;
    int i = blockIdx.x * 256 + threadIdx.x;
    int t = threadIdx.x, lane = t & 63, wv = t >> 6;
    int m = (i < N_NODES) ? (mask[i] != 0) : 0;
    unsigned long long bal = __ballot(m != 0);
    int pos = (int)__popcll(bal & ((1ull << lane) - 1ull));
    __shared__ int wsum[4];
    if (lane == 63) wsum[wv] = pos + m;
    __syncthreads();
    int woff = 0;
    for (int w = 0; w < wv; w++) woff += wsum[w];
    if (m) list[ms[blockIdx.x] + woff + pos] = i;
}

__global__ __launch_bounds__(256) void scan_phase3(
    int* __restrict__ bins_a, int* __restrict__ bins_b,
    const int* __restrict__ bs_a, const int* __restrict__ bs_b) {
    int* bins = blockIdx.y ? bins_b : bins_a;
    const int* bs = blockIdx.y ? bs_b : bs_a;
    int i = blockIdx.x * 256 + threadIdx.x;
    int t = threadIdx.x, lane = t & 63, wv = t >> 6;
    int v = (i < N_NODES) ? bins[i] : 0;
    int s = v;
#pragma unroll
    for (int off = 1; off < 64; off <<= 1) {
        int u = __shfl_up(s, off, 64);
        if (lane >= off) s += u;
    }
    __shared__ int wsum[4];
    if (lane == 63) wsum[wv] = s;
    __syncthreads();
    int woff = 0;
    for (int w = 0; w < wv; w++) woff += wsum[w];
    if (i < N_NODES) bins[i] = s - v + woff + bs[blockIdx.x];
}

// src reconstruction: node r owns [bins[r], bins[r+1]) — dense sequential fill.
// MUST run before scatter2 (which mutates bins).
__global__ void fill_src_kernel(const int* __restrict__ bins_a, const int* __restrict__ bins_b,
                                int* __restrict__ ssrc_a, int* __restrict__ ssrc_b) {
    const int* bins = blockIdx.y ? bins_b : bins_a;
    int* ssrc = blockIdx.y ? ssrc_b : ssrc_a;
    int r = blockIdx.x * 256 + threadIdx.x;
    if (r >= N_NODES) return;
    int p0 = bins[r], p1 = bins[r + 1];
    for (int p = p0; p < p1; p++) ssrc[p] = r;
}

// scatter: only the dst column (4B) goes through the random-position store
__global__ void scatter2_kernel(const int* __restrict__ ea, const int* __restrict__ eb,
                                const int* __restrict__ ma, const int* __restrict__ mb,
                                int* __restrict__ ba, int* __restrict__ bb,
                                int* __restrict__ sdst_a, int* __restrict__ sdst_b) {
    int half = gridDim.x >> 1;
    int b = blockIdx.x;
    const int* e; const int* mask; int* bins; int* sdst;
    if (b < half) { e = ea; mask = ma; bins = ba; sdst = sdst_a; }
    else          { e = eb; mask = mb; bins = bb; sdst = sdst_b; b -= half; }
    int i = b * 256 + threadIdx.x;
    if (i >= N_EDGES) return;
    int r = e[i];
    if (mask[r] == 0) return;
    int c = e[N_EDGES + i];
    int pos = atomicAdd(&bins[r], 1);
    sdst[pos] = c;
}

// ---------------------------------------------------------------------------
// emb_in: h0[N,64] @ W[64,128] + b -> h (fp32) and h_bf (bf16)
// ---------------------------------------------------------------------------
__global__ __launch_bounds__(256) void emb_in_kernel(
    const float* __restrict__ h0, const bf16_t* __restrict__ wp,
    const float* __restrict__ bias, float* __restrict__ h, bf16_t* __restrict__ h_bf)
{
    int t = threadIdx.x, wave = t >> 6, lane = t & 63;
    int quad = lane >> 4, col = lane & 15;
    int m0 = blockIdx.x * 64 + wave * 16;
    int ndc = min(m0 + col, N_NODES - 1);
    floatx4 acc[8] = {};
#pragma unroll
    for (int ks = 0; ks < 2; ks++) {
        const float* ap = h0 + ndc * 64 + ks * 32 + quad * 8;
        floatx4 f0 = *(const floatx4*)ap;
        floatx4 f1 = *(const floatx4*)(ap + 4);
        bf16x8 a;
#pragma unroll
        for (int j = 0; j < 4; j++) { a[j] = (bf16_t)f0[j]; a[j + 4] = (bf16_t)f1[j]; }
#pragma unroll
        for (int nt = 0; nt < 8; nt++) {
            bf16x8 b = ((const bf16x8*)wp)[(nt * 2 + ks) * 64 + lane];
            acc[nt] = __builtin_amdgcn_mfma_f32_16x16x32_bf16(a, b, acc[nt], 0, 0, 0);
        }
    }
#pragma unroll
    for (int r = 0; r < 4; r++) {
        int nd2 = m0 + quad * 4 + r;
        if (nd2 < N_NODES) {
#pragma unroll
            for (int nt = 0; nt < 8; nt++) {
                int n = nt * 16 + col;
                float x = acc[nt][r] + bias[n];
                h[nd2 * HID + n] = x;
                h_bf[nd2 * HID + n] = (bf16_t)x;
            }
        }
    }
}

// ---------------------------------------------------------------------------
// Sorted edge kernel (round-12 champion): static grid-stride tiles, prefetch
// pipeline, mbT-transposed combine, split ssrc/sdst inputs.
// ---------------------------------------------------------------------------
__global__ __launch_bounds__(256, 3) void edge_kernel_sorted(
    const bf16_t* __restrict__ h_bf, const int* __restrict__ ssrc,
    const int* __restrict__ sdst, const int* __restrict__ m_ptr,
    const bf16_t* __restrict__ w1p, const float* __restrict__ b1,
    const bf16_t* __restrict__ w2p, const float* __restrict__ b2,
    float* __restrict__ agg, float C)
{
    __shared__ __align__(16) bf16_t w1s[16384];        // 32 KB GEMM1 B-frags
    __shared__ __align__(16) bf16_t pool[4][64 * 40];  // per-wave hl/mbT union

    int t = threadIdx.x;
#pragma unroll
    for (int i = 0; i < 8; i++)
        ((bf16x8*)w1s)[t + 256 * i] = ((const bf16x8*)w1p)[t + 256 * i];
    __syncthreads();  // once

    int wave = t >> 6, lane = t & 63, quad = lane >> 4, col = lane & 15;
    bf16_t* hl = pool[wave];   // GEMM1->GEMM2 transpose, stride 72
    bf16_t* mbT = pool[wave];  // messages transposed [n][e], stride 40

    float b1v[4], b2v[4];
#pragma unroll
    for (int nt = 0; nt < 4; nt++) { b1v[nt] = b1[nt * 16 + col]; b2v[nt] = b2[nt * 16 + col]; }

    int M = m_ptr[0];
    int ntiles = (M + 31) >> 5;
    int wid = blockIdx.x * 4 + wave, nw = gridDim.x * 4;
    if (wid >= ntiles) return;

    // prologue: load tile wid's edges + gather its A-frags
    int sr = 0x7fffffff, ds = 0x7fffffff;
    { int p = wid * 32 + lane; if (lane < 32 && p < M) { sr = ssrc[p]; ds = sdst[p]; } }
    bf16x8 a[2][8];
    {
        int ns0 = min(__shfl(sr, col, 64), N_NODES - 1);
        int ns1 = min(__shfl(sr, 16 + col, 64), N_NODES - 1);
        int nd0 = min(__shfl(ds, col, 64), N_NODES - 1);
        int nd1 = min(__shfl(ds, 16 + col, 64), N_NODES - 1);
#pragma unroll
        for (int ks = 0; ks < 8; ks++) {
            int o = (ks & 3) * 32 + quad * 8;
            a[0][ks] = *(const bf16x8*)(h_bf + (ks < 4 ? ns0 : nd0) * HID + o);
            a[1][ks] = *(const bf16x8*)(h_bf + (ks < 4 ? ns1 : nd1) * HID + o);
        }
    }

    for (int tile = wid; tile < ntiles; tile += nw) {
        int tnc = min(tile + nw, ntiles - 1);
        int srn = 0x7fffffff, dsn = 0x7fffffff;
        { int p = tnc * 32 + lane; if (lane < 32 && p < M) { srn = ssrc[p]; dsn = sdst[p]; } }

        // GEMM1
        floatx4 acc[2][4] = {};
#pragma unroll
        for (int ks = 0; ks < 8; ks++) {
#pragma unroll
            for (int nt = 0; nt < 4; nt++) {
                bf16x8 b = ((const bf16x8*)w1s)[(nt * 8 + ks) * 64 + lane];
                acc[0][nt] = __builtin_amdgcn_mfma_f32_16x16x32_bf16(a[0][ks], b, acc[0][nt], 0, 0, 0);
                acc[1][nt] = __builtin_amdgcn_mfma_f32_16x16x32_bf16(a[1][ks], b, acc[1][nt], 0, 0, 0);
            }
        }

        // next tile's gathers — in flight under epilogues/GEMM2
        bf16x8 an[2][8];
        {
            int ns0 = min(__shfl(srn, col, 64), N_NODES - 1);
            int ns1 = min(__shfl(srn, 16 + col, 64), N_NODES - 1);
            int nd0 = min(__shfl(dsn, col, 64), N_NODES - 1);
            int nd1 = min(__shfl(dsn, 16 + col, 64), N_NODES - 1);
#pragma unroll
            for (int ks = 0; ks < 8; ks++) {
                int o = (ks & 3) * 32 + quad * 8;
                an[0][ks] = *(const bf16x8*)(h_bf + (ks < 4 ? ns0 : nd0) * HID + o);
                an[1][ks] = *(const bf16x8*)(h_bf + (ks < 4 ? ns1 : nd1) * HID + o);
            }
        }

        // epilogue1: C-layout -> A-layout (wave-local LDS, stride 72)
#pragma unroll
        for (int m = 0; m < 2; m++)
#pragma unroll
            for (int nt = 0; nt < 4; nt++)
#pragma unroll
                for (int r = 0; r < 4; r++)
                    hl[(m * 16 + quad * 4 + r) * 72 + nt * 16 + col] =
                        (bf16_t)silu_f(acc[m][nt][r] + b1v[nt]);

        floatx4 acc2[2][4] = {};
#pragma unroll
        for (int ks = 0; ks < 2; ks++) {
            bf16x8 a2[2];
#pragma unroll
            for (int m = 0; m < 2; m++)
                a2[m] = *(const bf16x8*)(hl + (m * 16 + col) * 72 + ks * 32 + quad * 8);
#pragma unroll
            for (int nt = 0; nt < 4; nt++) {
                bf16x8 b = ((const bf16x8*)w2p)[(nt * 2 + ks) * 64 + lane];
                acc2[0][nt] = __builtin_amdgcn_mfma_f32_16x16x32_bf16(a2[0], b, acc2[0][nt], 0, 0, 0);
                acc2[1][nt] = __builtin_amdgcn_mfma_f32_16x16x32_bf16(a2[1], b, acc2[1][nt], 0, 0, 0);
            }
        }
        // epilogue2: messages TRANSPOSED mbT[n][e], 4 r-values per b64 write
#pragma unroll
        for (int m = 0; m < 2; m++)
#pragma unroll
            for (int nt = 0; nt < 4; nt++) {
                ushort4v p;
#pragma unroll
                for (int r = 0; r < 4; r++) {
                    bf16_t bv = (bf16_t)(silu_f(acc2[m][nt][r] + b2v[nt]) * C);
                    p[r] = __builtin_bit_cast(unsigned short, bv);
                }
                *(ushort4v*)(mbT + (nt * 16 + col) * 40 + m * 16 + quad * 4) = p;
            }

        // combine: preload full column, then pure-VALU run-length scan
        {
            float mv[32];
#pragma unroll
            for (int i = 0; i < 4; i++) {
                bf16x8 v8 = *(const bf16x8*)(mbT + lane * 40 + i * 8);
#pragma unroll
                for (int j = 0; j < 8; j++) mv[i * 8 + j] = (float)v8[j];
            }
            int dp = __shfl(sr, 0, 64);
            float run = mv[0];
#pragma unroll
            for (int r = 1; r < 32; r++) {
                int d = __shfl(sr, r, 64);
                if (d != dp) {  // wave-uniform: coalesced atomic bursts
                    if (dp < N_NODES) atomicAdd(agg + dp * EH + lane, run);
                    run = mv[r]; dp = d;
                } else run += mv[r];
            }
            if (dp < N_NODES) atomicAdd(agg + dp * EH + lane, run);
        }

        sr = srn; ds = dsn;
#pragma unroll
        for (int m = 0; m < 2; m++)
#pragma unroll
            for (int ks = 0; ks < 8; ks++) a[m][ks] = an[m][ks];
    }
}

// ---------------------------------------------------------------------------
// Fallback (unsorted) edge kernel — used only if ws_size is too small.
// ---------------------------------------------------------------------------
__global__ __launch_bounds__(256) void edge_kernel(
    const bf16_t* __restrict__ h_bf, const int* __restrict__ edges,
    const int* __restrict__ mask,
    const bf16_t* __restrict__ w1p, const float* __restrict__ b1,
    const bf16_t* __restrict__ w2p, const float* __restrict__ b2,
    float* __restrict__ agg, float C)
{
    __shared__ __align__(16) bf16_t w1s[16384];
    __shared__ __align__(16) bf16_t w2s[4096];
    __shared__ __align__(16) bf16_t hl[4][16 * 72];

    int t = threadIdx.x;
#pragma unroll
    for (int i = 0; i < 8; i++)
        ((bf16x8*)w1s)[t + 256 * i] = ((const bf16x8*)w1p)[t + 256 * i];
#pragma unroll
    for (int i = 0; i < 2; i++)
        ((bf16x8*)w2s)[t + 256 * i] = ((const bf16x8*)w2p)[t + 256 * i];
    __syncthreads();

    int wave = t >> 6, lane = t & 63, quad = lane >> 4, col = lane & 15;
    bf16_t* myhl = hl[wave];

    float b1v[4], b2v[4];
#pragma unroll
    for (int nt = 0; nt < 4; nt++) { b1v[nt] = b1[nt * 16 + col]; b2v[nt] = b2[nt * 16 + col]; }

    const int ntile_cnt = N_EDGES / 64;
    for (int tile = blockIdx.x; tile < ntile_cnt; tile += gridDim.x) {
        int ebase = tile * 64 + wave * 16;
        int src = edges[ebase + col];
        int dst = edges[N_EDGES + ebase + col];

        floatx4 acc[4] = {};
#pragma unroll
        for (int ks = 0; ks < 8; ks++) {
            int idx = (ks < 4) ? src : dst;
            bf16x8 a = *(const bf16x8*)(h_bf + idx * HID + (ks & 3) * 32 + quad * 8);
#pragma unroll
            for (int nt = 0; nt < 4; nt++) {
                bf16x8 b = ((const bf16x8*)w1s)[(nt * 8 + ks) * 64 + lane];
                acc[nt] = __builtin_amdgcn_mfma_f32_16x16x32_bf16(a, b, acc[nt], 0, 0, 0);
            }
        }
#pragma unroll
        for (int nt = 0; nt < 4; nt++)
#pragma unroll
            for (int r = 0; r < 4; r++)
                myhl[(quad * 4 + r) * 72 + nt * 16 + col] = (bf16_t)silu_f(acc[nt][r] + b1v[nt]);
        __syncthreads();

        floatx4 acc2[4] = {};
#pragma unroll
        for (int ks = 0; ks < 2; ks++) {
            bf16x8 a = *(const bf16x8*)(myhl + col * 72 + ks * 32 + quad * 8);
#pragma unroll
            for (int nt = 0; nt < 4; nt++) {
                bf16x8 b = ((const bf16x8*)w2s)[(nt * 2 + ks) * 64 + lane];
                acc2[nt] = __builtin_amdgcn_mfma_f32_16x16x32_bf16(a, b, acc2[nt], 0, 0, 0);
            }
        }
#pragma unroll
        for (int r = 0; r < 4; r++) {
            int dest = edges[ebase + quad * 4 + r];
            if (mask[dest] != 0) {
                float* aggp = agg + dest * EH;
#pragma unroll
                for (int nt = 0; nt < 4; nt++) {
                    float x = acc2[nt][r] + b2v[nt];
                    atomicAdd(aggp + nt * 16 + col, silu_f(x) * C);
                }
            }
        }
        __syncthreads();
    }
}

// ---------------------------------------------------------------------------
// Masked node kernel (layers 0..2): processes ONLY listed (masked) nodes.
// Unconditional residual update; zeroes exactly the agg rows it consumed.
// ---------------------------------------------------------------------------
__global__ __launch_bounds__(256) void node_kernel_masked(
    float* __restrict__ h, bf16_t* __restrict__ h_bf,
    float* __restrict__ agg, const int* __restrict__ list,
    const int* __restrict__ cnt_ptr,
    const bf16_t* __restrict__ w1p, const float* __restrict__ b1,
    const bf16_t* __restrict__ w2p, const float* __restrict__ b2)
{
    __shared__ __align__(16) bf16_t hl[4][16 * 136];
    int t = threadIdx.x, wave = t >> 6, lane = t & 63;
    int quad = lane >> 4, col = lane & 15;
    int cnt = cnt_ptr[0];
    int m0 = blockIdx.x * 64 + wave * 16;
    if (m0 >= cnt) return;  // wave-level exit; no block barriers below
    int lv = list[min(m0 + col, cnt - 1)];  // node id for this col
    int ndc = lv;

    floatx4 acc[8] = {};
#pragma unroll
    for (int ks = 0; ks < 6; ks++) {
        bf16x8 a;
        if (ks < 4) {
            a = *(const bf16x8*)(h_bf + ndc * HID + ks * 32 + quad * 8);
        } else {
            const float* ap = agg + ndc * EH + (ks - 4) * 32 + quad * 8;
            floatx4 f0 = *(const floatx4*)ap;
            floatx4 f1 = *(const floatx4*)(ap + 4);
#pragma unroll
            for (int j = 0; j < 4; j++) { a[j] = (bf16_t)f0[j]; a[j + 4] = (bf16_t)f1[j]; }
        }
#pragma unroll
        for (int nt = 0; nt < 8; nt++) {
            bf16x8 b = ((const bf16x8*)w1p)[(nt * 6 + ks) * 64 + lane];
            acc[nt] = __builtin_amdgcn_mfma_f32_16x16x32_bf16(a, b, acc[nt], 0, 0, 0);
        }
    }
    // zero this node's agg row for the next layer (unique unclamped owner)
    if ((m0 + col) < cnt) {
        floatx4 z = {0.0f, 0.0f, 0.0f, 0.0f};
        float* zp = agg + ndc * EH + quad * 8;
        *(floatx4*)zp = z; *(floatx4*)(zp + 4) = z;
        *(floatx4*)(zp + 32) = z; *(floatx4*)(zp + 36) = z;
    }
    bf16_t* myhl = hl[wave];
#pragma unroll
    for (int nt = 0; nt < 8; nt++)
#pragma unroll
        for (int r = 0; r < 4; r++) {
            float x = acc[nt][r] + b1[nt * 16 + col];
            myhl[(quad * 4 + r) * 136 + nt * 16 + col] = (bf16_t)silu_f(x);
        }
    // no barrier: myhl is wave-local, DS ops in-order per wave

    floatx4 acc2[8] = {};
#pragma unroll
    for (int ks = 0; ks < 4; ks++) {
        bf16x8 a = *(const bf16x8*)(myhl + col * 136 + ks * 32 + quad * 8);
#pragma unroll
        for (int nt = 0; nt < 8; nt++) {
            bf16x8 b = ((const bf16x8*)w2p)[(nt * 4 + ks) * 64 + lane];
            acc2[nt] = __builtin_amdgcn_mfma_f32_16x16x32_bf16(a, b, acc2[nt], 0, 0, 0);
        }
    }
#pragma unroll
    for (int r = 0; r < 4; r++) {
        if ((m0 + quad * 4 + r) < cnt) {
            int nd2 = __shfl(lv, quad * 4 + r, 64);  // lanes 0..15 hold cols 0..15
#pragma unroll
            for (int nt = 0; nt < 8; nt++) {
                int n = nt * 16 + col;
                float hv = h[nd2 * HID + n] + acc2[nt][r] + b2[n];
                h[nd2 * HID + n] = hv;
                h_bf[nd2 * HID + n] = (bf16_t)hv;
            }
        }
    }
}

// ---------------------------------------------------------------------------
// Full node kernel (layer 3): masked update + fused emb_out for ALL nodes.
// ---------------------------------------------------------------------------
__global__ __launch_bounds__(256) void node_kernel(
    float* __restrict__ h, bf16_t* __restrict__ h_bf,
    float* __restrict__ agg, const int* __restrict__ mask,
    const bf16_t* __restrict__ w1p, const float* __restrict__ b1,
    const bf16_t* __restrict__ w2p, const float* __restrict__ b2,
    const bf16_t* __restrict__ wop, const float* __restrict__ bo,
    float* __restrict__ out)
{
    __shared__ __align__(16) bf16_t hl[4][16 * 136];
    int t = threadIdx.x, wave = t >> 6, lane = t & 63;
    int quad = lane >> 4, col = lane & 15;
    int m0 = blockIdx.x * 64 + wave * 16;
    int ndc = min(m0 + col, N_NODES - 1);

    floatx4 acc[8] = {};
#pragma unroll
    for (int ks = 0; ks < 6; ks++) {
        bf16x8 a;
        if (ks < 4) {
            a = *(const bf16x8*)(h_bf + ndc * HID + ks * 32 + quad * 8);
        } else {
            const float* ap = agg + ndc * EH + (ks - 4) * 32 + quad * 8;
            floatx4 f0 = *(const floatx4*)ap;
            floatx4 f1 = *(const floatx4*)(ap + 4);
#pragma unroll
            for (int j = 0; j < 4; j++) { a[j] = (bf16_t)f0[j]; a[j + 4] = (bf16_t)f1[j]; }
        }
#pragma unroll
        for (int nt = 0; nt < 8; nt++) {
            bf16x8 b = ((const bf16x8*)w1p)[(nt * 6 + ks) * 64 + lane];
            acc[nt] = __builtin_amdgcn_mfma_f32_16x16x32_bf16(a, b, acc[nt], 0, 0, 0);
        }
    }
    bf16_t* myhl = hl[wave];
#pragma unroll
    for (int nt = 0; nt < 8; nt++)
#pragma unroll
        for (int r = 0; r < 4; r++) {
            float x = acc[nt][r] + b1[nt * 16 + col];
            myhl[(quad * 4 + r) * 136 + nt * 16 + col] = (bf16_t)silu_f(x);
        }

    floatx4 acc2[8] = {};
#pragma unroll
    for (int ks = 0; ks < 4; ks++) {
        bf16x8 a = *(const bf16x8*)(myhl + col * 136 + ks * 32 + quad * 8);
#pragma unroll
        for (int nt = 0; nt < 8; nt++) {
            bf16x8 b = ((const bf16x8*)w2p)[(nt * 4 + ks) * 64 + lane];
            acc2[nt] = __builtin_amdgcn_mfma_f32_16x16x32_bf16(a, b, acc2[nt], 0, 0, 0);
        }
    }
#pragma unroll
    for (int r = 0; r < 4; r++) {
        int nd2 = m0 + quad * 4 + r;
        bool valid = nd2 < N_NODES;
        bool upd = valid && mask[min(nd2, N_NODES - 1)] != 0;
        if (upd) {
#pragma unroll
            for (int nt = 0; nt < 8; nt++) {
                int n = nt * 16 + col;
                float hv = h[nd2 * HID + n] + acc2[nt][r] + b2[n];
                h[nd2 * HID + n] = hv;
                bf16_t hb = (bf16_t)hv;
                h_bf[nd2 * HID + n] = hb;
                myhl[(quad * 4 + r) * 136 + n] = hb;
            }
        } else {
#pragma unroll
            for (int nt = 0; nt < 8; nt++) {
                int n = nt * 16 + col;
                myhl[(quad * 4 + r) * 136 + n] =
                    valid ? h_bf[nd2 * HID + n] : (bf16_t)0.0f;
            }
        }
    }
    // fused emb_out: out = h_final @ W_out + b_out
    floatx4 ao[4] = {};
#pragma unroll
    for (int ks = 0; ks < 4; ks++) {
        bf16x8 a = *(const bf16x8*)(myhl + col * 136 + ks * 32 + quad * 8);
#pragma unroll
        for (int nt = 0; nt < 4; nt++) {
            bf16x8 b = ((const bf16x8*)wop)[(nt * 4 + ks) * 64 + lane];
            ao[nt] = __builtin_amdgcn_mfma_f32_16x16x32_bf16(a, b, ao[nt], 0, 0, 0);
        }
    }
#pragma unroll
    for (int r = 0; r < 4; r++) {
        int nd2 = m0 + quad * 4 + r;
        if (nd2 < N_NODES) {
#pragma unroll
            for (int nt = 0; nt < 4; nt++) {
                int n = nt * 16 + col;
                out[nd2 * 64 + n] = ao[nt][r] + bo[n];
            }
        }
    }
}

extern "C" void kernel_launch(void* const* d_in, const int* in_sizes, int n_in,
                              void* d_out, int out_size, void* d_ws, size_t ws_size,
                              hipStream_t stream) {
    const float* h0        = (const float*)d_in[0];
    const int*   edges_a   = (const int*)d_in[1];
    const int*   edges_b   = (const int*)d_in[2];
    const int*   mask_a    = (const int*)d_in[3];
    const int*   mask_b    = (const int*)d_in[4];
    const float* emb_in_w  = (const float*)d_in[5];
    const float* emb_in_b  = (const float*)d_in[6];
    const float* emb_out_w = (const float*)d_in[7];
    const float* emb_out_b = (const float*)d_in[8];
    const float* ew1 = (const float*)d_in[9];
    const float* eb1 = (const float*)d_in[10];
    const float* ew2 = (const float*)d_in[11];
    const float* eb2 = (const float*)d_in[12];
    const float* nw1 = (const float*)d_in[13];
    const float* nb1 = (const float*)d_in[14];
    const float* nw2 = (const float*)d_in[15];
    const float* nb2 = (const float*)d_in[16];

    const size_t SZ_H = 25600000, SZ_HBF = 12800000, SZ_AGG = 12800000, SZ_PK = 524288;
    const size_t SZ_S = 3200000, SZ_BINS = 200704, SZ_BS = 1024, SZ_LIST = 200704;

    char* ws = (char*)d_ws;
    size_t off = 0;
    float*  h    = (float*)(ws + off);  off += SZ_H;
    bf16_t* h_bf = (bf16_t*)(ws + off); off += SZ_HBF;
    float*  agg  = (float*)(ws + off);  off += SZ_AGG;
    bf16_t* pk   = (bf16_t*)(ws + off); off += SZ_PK;
    int* ssrc_a = (int*)(ws + off); off += SZ_S;
    int* sdst_a = (int*)(ws + off); off += SZ_S;
    int* ssrc_b = (int*)(ws + off); off += SZ_S;
    int* sdst_b = (int*)(ws + off); off += SZ_S;
    int* bins_a = (int*)(ws + off); off += SZ_BINS;  // bins..bs contiguous -> one memset
    int* bins_b = (int*)(ws + off); off += SZ_BINS;
    int* bs_a   = (int*)(ws + off); off += SZ_BS;
    int* bs_b   = (int*)(ws + off); off += SZ_BS;
    int* ms_a   = (int*)(ws + off); off += SZ_BS;    // mask-chunk sums (no zeroing needed)
    int* ms_b   = (int*)(ws + off); off += SZ_BS;
    int* cnt_a  = (int*)(ws + off); off += 256;
    int* cnt_b  = (int*)(ws + off); off += 256;
    int* list_a = (int*)(ws + off); off += SZ_LIST;
    int* list_b = (int*)(ws + off); off += SZ_LIST;
    bool sorted_path = (ws_size >= off);

    bf16_t* pk_embin  = pk;
    bf16_t* pk_embout = pk + 8192;
    bf16_t* pk_ew1    = pk + 16384;
    bf16_t* pk_ew2    = pk + 81920;
    bf16_t* pk_nw1    = pk + 98304;
    bf16_t* pk_nw2    = pk + 196608;

    pack_all_kernel<<<128, 256, 0, stream>>>(emb_in_w, emb_out_w, ew1, ew2, nw1, nw2, pk);

    const int edge_grid = (N_EDGES + 255) / 256;  // 3125
    const int node_blocks = (N_NODES + 63) / 64;  // 782
    if (sorted_path) {
        hipMemsetAsync(bins_a, 0, 2 * SZ_BINS + 2 * SZ_BS, stream);
        hist2_kernel<<<2 * edge_grid, 256, 0, stream>>>(edges_a, edges_b, mask_a, mask_b,
                                                        bins_a, bins_b);
        scan_phase1<<<dim3(NCH, 2), 256, 0, stream>>>(bins_a, bins_b, bs_a, bs_b);
        scan_phase2<<<2, 256, 0, stream>>>(bs_a, bs_b, bins_a, bins_b);
        scan_phase3<<<dim3(NCH, 2), 256, 0, stream>>>(bins_a, bins_b, bs_a, bs_b);
        fill_src_kernel<<<dim3(NCH, 2), 256, 0, stream>>>(bins_a, bins_b, ssrc_a, ssrc_b);
        scatter2_kernel<<<2 * edge_grid, 256, 0, stream>>>(edges_a, edges_b, mask_a, mask_b,
                                                           bins_a, bins_b, sdst_a, sdst_b);
        // masked-node compaction (lists in ascending node order)
        scan_phase1<<<dim3(NCH, 2), 256, 0, stream>>>(mask_a, mask_b, ms_a, ms_b);
        mask_scan2<<<2, 256, 0, stream>>>(ms_a, ms_b, cnt_a, cnt_b);
        compact_kernel<<<dim3(NCH, 2), 256, 0, stream>>>(mask_a, mask_b, ms_a, ms_b,
                                                         list_a, list_b);
    }

    hipMemsetAsync(agg, 0, (size_t)N_NODES * EH * 4, stream);  // once; node zeroes after
    emb_in_kernel<<<node_blocks, 256, 0, stream>>>(h0, pk_embin, emb_in_b, h, h_bf);

    for (int l = 0; l < 4; l++) {
        const int* mask = (l & 1) ? mask_b : mask_a;
        float C = (l & 1) ? 0.03125f : 1.0f;
        if (sorted_path) {
            const int* ssrc = (l & 1) ? ssrc_b : ssrc_a;
            const int* sdst = (l & 1) ? sdst_b : sdst_a;
            const int* mp   = ((l & 1) ? bins_b : bins_a) + N_NODES;
            edge_kernel_sorted<<<768, 256, 0, stream>>>(h_bf, ssrc, sdst, mp,
                                                        pk_ew1 + l * 16384, eb1 + l * 64,
                                                        pk_ew2 + l * 4096,  eb2 + l * 64,
                                                        agg, C);
        } else {
            const int* edges = (l & 1) ? edges_b : edges_a;
            edge_kernel<<<768, 256, 0, stream>>>(h_bf, edges, mask,
                                                 pk_ew1 + l * 16384, eb1 + l * 64,
                                                 pk_ew2 + l * 4096,  eb2 + l * 64,
                                                 agg, C);
        }
        if (l < 3 && sorted_path) {
            const int* list = (l & 1) ? list_b : list_a;
            const int* cnt  = (l & 1) ? cnt_b : cnt_a;
            node_kernel_masked<<<node_blocks, 256, 0, stream>>>(
                h, h_bf, agg, list, cnt,
                pk_nw1 + l * 24576, nb1 + l * 128,
                pk_nw2 + l * 16384, nb2 + l * 128);
        } else if (l < 3) {
            // fallback: full node kernel without fused out (reuse masked-free path)
            node_kernel<<<node_blocks, 256, 0, stream>>>(h, h_bf, agg, mask,
                                                         pk_nw1 + l * 24576, nb1 + l * 128,
                                                         pk_nw2 + l * 16384, nb2 + l * 128,
                                                         pk_embout, emb_out_b, (float*)d_out);
            hipMemsetAsync(agg, 0, (size_t)N_NODES * EH * 4, stream);
        } else {
            node_kernel<<<node_blocks, 256, 0, stream>>>(h, h_bf, agg, mask,
                                                         pk_nw1 + 3 * 24576, nb1 + 3 * 128,
                                                         pk_nw2 + 3 * 16384, nb2 + 3 * 128,
                                                         pk_embout, emb_out_b, (float*)d_out);
        }
    }
}